// Round 2
// baseline (482.812 us; speedup 1.0000x reference)
//
#include <hip/hip_runtime.h>
#include <math.h>

#define BB   256     // batch
#define NN0  400     // nodes at layer 1
#define NE   79800   // NN0*(NN0-1)/2
#define EPSF 1e-5f

// ---------- device helpers ----------
__device__ __forceinline__ int tri_e(int a, int c) {  // a<c, upper-tri flat index
  return a*(NN0-1) - ((a*(a-1))>>1) + (c - a - 1);
}

__device__ __forceinline__ size_t PRI(int b, int ti, int tj, int r) {
  return (((size_t)b*7 + ti)*7 + tj)*64 + r;
}

__device__ __forceinline__ float wave_sum(float v) {
  #pragma unroll
  for (int o = 32; o > 0; o >>= 1) v += __shfl_xor(v, o, 64);
  return v;
}

// descending bitonic sort (score desc, idx asc == jax.lax.top_k order)
__device__ __forceinline__ void bitonic_desc(float* sc, int* si, int P) {
  const int tid = threadIdx.x;
  const int nt = blockDim.x;
  for (int k = 2; k <= P; k <<= 1) {
    for (int j = k >> 1; j > 0; j >>= 1) {
      __syncthreads();
      for (int i = tid; i < P; i += nt) {
        int ixj = i ^ j;
        if (ixj > i) {
          float a = sc[i], c = sc[ixj];
          int ai = si[i], ci = si[ixj];
          bool bef = (a > c) || (a == c && ai < ci);
          bool sw = ((i & k) == 0) ? !bef : bef;
          if (sw) { sc[i] = c; sc[ixj] = a; si[i] = ci; si[ixj] = ai; }
        }
      }
    }
  }
  __syncthreads();
}

// ---------- K1: dense symmetric tri-matvec partials (NO atomics) ----------
__global__ __launch_bounds__(256) void k_tri_mv(
    const float* __restrict__ data,
    const float* __restrict__ pr_in, const float* __restrict__ pc_in,
    float* __restrict__ pr, float* __restrict__ pc) {
  __shared__ float tile[64][65];
  __shared__ float dI[64], dJ[64];
  const int q0 = blockIdx.x % 7, b = blockIdx.x / 7;
  const int tid = threadIdx.x;
  const int wave = tid >> 6, lane = tid & 63;
  const float* __restrict__ drow = data + (size_t)b*NE;
  int ti_a[4], tj_a[4];
  #pragma unroll
  for (int u = 0; u < 4; ++u) {
    int t = q0 + u*7;
    int ti = 0, rem = t;
    while (rem >= 7 - ti) { rem -= 7 - ti; ++ti; }
    ti_a[u] = ti; tj_a[u] = ti + rem;
  }
  float vreg[16];
  float rI = 0.f, rJ = 0.f;
  auto issue = [&](int u) {
    const int i0 = ti_a[u]*64, j0 = tj_a[u]*64;
    const int ni = min(64, NN0 - i0), nj = min(64, NN0 - j0);
    #pragma unroll
    for (int k = 0; k < 16; ++k) {
      const int rr = wave*16 + k;
      const int i = i0 + rr, j = j0 + lane;
      vreg[k] = 0.f;
      if (rr < ni && lane < nj && j > i) vreg[k] = drow[tri_e(i, j)];
    }
    if (pr_in) {
      if (tid < 64) {
        float a = 0.f;
        if (tid < ni) {
          const int tt = ti_a[u], r = tid;
          float acc = 1.f;
          for (int tj = tt; tj < 7; ++tj) acc += pr_in[PRI(b, tt, tj, r)];
          for (int ts = 0; ts <= tt; ++ts) acc += pc_in[PRI(b, ts, tt, r)];
          a = rsqrtf(acc);
        }
        rI = a;
      } else if (tid < 128) {
        const int c = tid - 64;
        float a = 0.f;
        if (c < nj) {
          const int tt = tj_a[u], r = c;
          float acc = 1.f;
          for (int tj = tt; tj < 7; ++tj) acc += pr_in[PRI(b, tt, tj, r)];
          for (int ts = 0; ts <= tt; ++ts) acc += pc_in[PRI(b, ts, tt, r)];
          a = rsqrtf(acc);
        }
        rJ = a;
      }
    } else {
      if (tid < 64) rI = (tid < ni) ? 1.f : 0.f;
      else if (tid < 128) rJ = (tid - 64 < nj) ? 1.f : 0.f;
    }
  };
  issue(0);
  #pragma unroll 1
  for (int u = 0; u < 4; ++u) {
    const int ti = ti_a[u], tj = tj_a[u];
    if (u) __syncthreads();
    #pragma unroll
    for (int k = 0; k < 16; ++k) tile[wave*16 + k][lane] = vreg[k];
    if (tid < 64) dI[tid] = rI;
    else if (tid < 128) dJ[tid-64] = rJ;
    __syncthreads();
    if (u + 1 < 4) issue(u + 1);
    {
      const int r = tid >> 2, q = tid & 3;
      float s = 0.f;
      #pragma unroll
      for (int c = 0; c < 16; ++c) s += tile[r][q*16 + c] * dJ[q*16 + c];
      s += __shfl_xor(s, 1, 64);
      s += __shfl_xor(s, 2, 64);
      if (q == 0) pr[PRI(b, ti, tj, r)] = s;
    }
    {
      const int c = tid >> 2, q = tid & 3;
      float s = 0.f;
      #pragma unroll
      for (int r = 0; r < 16; ++r) s += tile[q*16 + r][c] * dI[q*16 + r];
      s += __shfl_xor(s, 1, 64);
      s += __shfl_xor(s, 2, 64);
      if (q == 0) pc[PRI(b, ti, tj, c)] = s;
    }
  }
}

// ---------- K2: reduce deg & s partials -> s1, + BN stats via global atomics ----------
__global__ __launch_bounds__(256) void k_sfin_stats_red(
    const float* __restrict__ pr, const float* __restrict__ pc,
    const float* __restrict__ pr2, const float* __restrict__ pc2,
    const float* __restrict__ W1, const float* __restrict__ b1,
    float* __restrict__ s1, float* __restrict__ acc1) {
  __shared__ float sl[256];
  __shared__ float st[64];
  __shared__ float w1s[32], b1s[32];
  const int tid = threadIdx.x;
  const int i = blockIdx.x*256 + tid;
  if (tid < 32) { w1s[tid] = W1[tid]; b1s[tid] = b1[tid]; }
  if (tid < 64) st[tid] = 0.f;
  const int b = i / NN0, n = i % NN0;
  const int t = n >> 6, r = n & 63;
  float dacc = 1.f, sacc = 0.f;
  for (int tj = t; tj < 7; ++tj) { dacc += pr[PRI(b, t, tj, r)]; sacc += pr2[PRI(b, t, tj, r)]; }
  for (int ti = 0; ti <= t; ++ti) { dacc += pc[PRI(b, ti, t, r)]; sacc += pc2[PRI(b, ti, t, r)]; }
  const float d = rsqrtf(dacc);
  const float s = d * (d + sacc);
  s1[i] = s;
  sl[tid] = s;
  __syncthreads();
  const int f = tid & 31, sub = tid >> 5;
  const float w = w1s[f], bb = b1s[f];
  float S = 0.f, Q = 0.f;
  #pragma unroll
  for (int k = 0; k < 32; ++k) {
    const float ss = sl[sub*32 + k];
    const float h = fmaxf(ss*w + bb, 0.f);
    S += h; Q += h*h;
  }
  atomicAdd(&st[f], S);
  atomicAdd(&st[32+f], Q);
  __syncthreads();
  if (tid < 64) atomicAdd(&acc1[tid], st[tid]);
}

// ---------- K3: inline BN-coeffs + layer-1 score + top-200 + Y2 = X2@W2 + perm ----------
__global__ __launch_bounds__(512) void k_top1(
    const float* __restrict__ s1, const float* __restrict__ acc1,
    const float* __restrict__ W1, const float* __restrict__ b1,
    const float* __restrict__ g1, const float* __restrict__ be1,
    const float* __restrict__ p1, const float* __restrict__ W2,
    int* __restrict__ nodes2, int* __restrict__ sperm2, float* __restrict__ Y2) {
  __shared__ float sc[512]; __shared__ int si[512];
  __shared__ float sS[NN0];
  __shared__ float tvs[200];
  __shared__ int nds_l[200];
  __shared__ float w1s[32], b1s[32], cfs[32], scs[32], shs[32];
  __shared__ __align__(16) float hp[6400];
  __shared__ float c0s;
  const int tid = threadIdx.x, b = blockIdx.x;
  if (tid < 32) { w1s[tid] = W1[tid]; b1s[tid] = b1[tid]; }
  if (tid < 64) {                       // inlined fin1
    float scale = 0.f, shift = 0.f, pv = 0.f;
    if (tid < 32) {
      const float S = acc1[tid], Q = acc1[32 + tid];
      const float N = 102400.f;
      const float mu = S / N;
      const float var = Q / N - mu*mu;
      const float inv = rsqrtf(var + EPSF);
      scale = inv * g1[tid];
      shift = be1[tid] - mu * scale;
      pv = p1[tid];
    }
    const float pn = sqrtf(wave_sum(pv*pv));
    if (tid < 32) { scs[tid] = scale; shs[tid] = shift; cfs[tid] = scale*pv/pn; }
    float u = (tid < 32) ? shift*pv/pn : 0.f;
    u = wave_sum(u);
    if (tid == 0) c0s = u;
  }
  __syncthreads();
  const float c0 = c0s;
  for (int i = tid; i < 512; i += 512) {
    if (i < NN0) {
      const float s = s1[(size_t)b*NN0 + i];
      sS[i] = s;
      float sco = c0;
      #pragma unroll
      for (int f = 0; f < 32; ++f) sco += fmaxf(s*w1s[f] + b1s[f], 0.f) * cfs[f];
      sc[i] = sco; si[i] = i;
    } else { sc[i] = -INFINITY; si[i] = 0x7fffffff; }
  }
  bitonic_desc(sc, si, 512);
  for (int k = tid; k < 200; k += 512) {
    tvs[k] = tanhf(sc[k]);
    nds_l[k] = si[k];
    nodes2[b*200 + k] = si[k];
  }
  __syncthreads();
  for (int o = tid; o < 6400; o += 512) {
    const int k = o >> 5, f = o & 31;
    const float s = sS[nds_l[k]];
    const float h = fmaxf(s*w1s[f] + b1s[f], 0.f);
    hp[o] = (h*scs[f] + shs[f]) * tvs[k];
  }
  __syncthreads();
  // Y2 = X2 @ W2 (unscaled; dis2 folded into conv2)
  {
    const int g = tid & 63;
    float wr[32];
    #pragma unroll
    for (int f = 0; f < 32; ++f) wr[f] = W2[f*64 + g];
    for (int o = tid; o < 12800; o += 512) {
      const int k = o >> 6;
      float acc = 0.f;
      #pragma unroll
      for (int c4 = 0; c4 < 8; ++c4) {
        const float4 x4 = *(const float4*)&hp[(k<<5) + (c4<<2)];
        acc += x4.x*wr[c4*4] + x4.y*wr[c4*4+1] + x4.z*wr[c4*4+2] + x4.w*wr[c4*4+3];
      }
      Y2[(size_t)b*12800 + o] = acc;
    }
  }
  __syncthreads();
  if (tid < 256) {
    sc[tid] = (tid < 200) ? -(float)nds_l[tid] : -INFINITY;
    si[tid] = (tid < 200) ? tid : 0x7fffffff;
  }
  bitonic_desc(sc, si, 256);
  if (tid < 200) sperm2[b*200 + tid] = si[tid];
}

// ---------- K4: gather A2 (sorted-id order, XCD-swizzled) + dis2 ----------
__global__ __launch_bounds__(256) void k_gatherA2(
    const float* __restrict__ data, const int* __restrict__ nodes2,
    const int* __restrict__ sperm2, float* __restrict__ A2, float* __restrict__ dis2) {
  __shared__ int nds[200], sp[200], sn[200];
  __shared__ float rowbuf[4][200];
  const int idx = blockIdx.x;
  const int r9 = idx >> 3;
  const int b = (idx & 7)*32 + r9/50;
  const int rg = r9 % 50;
  const int tid = threadIdx.x;
  if (tid < 200) { nds[tid] = nodes2[b*200 + tid]; sp[tid] = sperm2[b*200 + tid]; }
  __syncthreads();
  if (tid < 200) sn[tid] = nds[sp[tid]];
  __syncthreads();
  const int wave = tid >> 6, lane = tid & 63;
  const int i = rg*4 + wave;
  const int ni = nds[i];
  const float* __restrict__ drow = data + (size_t)b*NE;
  float accd = 0.f;
  for (int jj = lane; jj < 200; jj += 64) {
    const int sj = sn[jj];
    float v = 0.f;
    if (sj != ni) {
      const int a = min(ni, sj), c = max(ni, sj);
      v = drow[tri_e(a, c)];
    }
    rowbuf[wave][sp[jj]] = v;
    accd += v;
  }
  __syncthreads();
  for (int j = lane; j < 200; j += 64)
    A2[((size_t)b*200 + i)*200 + j] = rowbuf[wave][j];
  accd = wave_sum(accd);
  if (lane == 0) dis2[b*200 + i] = rsqrtf(1.f + accd);
}

// ---------- K5: conv2, lane-owns-feature structure ----------
// grid = BB*7; block p owns rows [p*32, p*32+32). wave w owns 8 rows, lane = feat.
// Per k-step: 1 ds_read_b32 (z) + 2 uniform ds_read_b128 (A bcast) + 8 FMA.
__global__ __launch_bounds__(256) void k_conv2(
    const float* __restrict__ A2, const float* __restrict__ Y2,
    const float* __restrict__ dis2, const float* __restrict__ b2,
    float* __restrict__ h2g, float* __restrict__ acc2g) {
  __shared__ __align__(16) float zb[40*64];   // 10.24 KB  [js][feat], dis-scaled
  __shared__ __align__(16) float ab[40*32];   // 5.12 KB   [js][local row]
  __shared__ float st[128];
  const int tid = threadIdx.x;
  const int b = blockIdx.x / 7, p = blockIdx.x % 7;
  const int wave = tid >> 6, lane = tid & 63;
  const int r0 = p*32;
  if (tid < 128) st[tid] = 0.f;
  const float bl = b2[lane];
  float acc[8] = {0,0,0,0,0,0,0,0};
  #pragma unroll 1
  for (int s = 0; s < 5; ++s) {
    const int j0 = s*40;
    if (s) __syncthreads();
    // zb: dis-scaled Y2 strip, [js][feat]
    for (int t = tid; t < 640; t += 256) {
      const int js = t >> 4, f4 = t & 15;
      const float dz = dis2[b*200 + j0 + js];
      float4 v = *(const float4*)&Y2[((size_t)b*200 + (j0 + js))*64 + (f4 << 2)];
      v.x *= dz; v.y *= dz; v.z *= dz; v.w *= dz;
      *(float4*)&zb[(js << 6) + (f4 << 2)] = v;
    }
    // ab: A2 col-band as row-band (symmetry), [js][32 local rows]
    for (int t = tid; t < 320; t += 256) {
      const int js = t >> 3, c4 = t & 7;
      const int col = r0 + (c4 << 2);
      float4 v = make_float4(0.f, 0.f, 0.f, 0.f);
      if (col <= 196)
        v = *(const float4*)&A2[((size_t)b*200 + (j0 + js))*200 + col];
      *(float4*)&ab[(js << 5) + (c4 << 2)] = v;
    }
    __syncthreads();
    #pragma unroll 4
    for (int js = 0; js < 40; ++js) {
      const float z = zb[(js << 6) + lane];
      const float4 a0 = *(const float4*)&ab[(js << 5) + (wave << 3)];
      const float4 a1 = *(const float4*)&ab[(js << 5) + (wave << 3) + 4];
      acc[0] += a0.x*z; acc[1] += a0.y*z; acc[2] += a0.z*z; acc[3] += a0.w*z;
      acc[4] += a1.x*z; acc[5] += a1.y*z; acc[6] += a1.z*z; acc[7] += a1.w*z;
    }
  }
  float ss = 0.f, qq = 0.f;
  #pragma unroll
  for (int k = 0; k < 8; ++k) {
    const int r = r0 + (wave << 3) + k;
    if (r < 200) {
      const float d = dis2[b*200 + r];
      const float y = Y2[((size_t)b*200 + r)*64 + lane];
      const float h = fmaxf(d*acc[k] + d*d*y + bl, 0.f);
      h2g[((size_t)b*200 + r)*64 + lane] = h;
      ss += h; qq += h*h;
    }
  }
  atomicAdd(&st[lane], ss);
  atomicAdd(&st[64 + lane], qq);
  __syncthreads();
  if (tid < 128) atomicAdd(&acc2g[tid], st[tid]);
}

// ---------- K6: inline BN-coeffs + layer-2 score + top-100 + Y3 = X3@W3 ----------
__global__ __launch_bounds__(512) void k_top2(
    const float* __restrict__ h2g, const float* __restrict__ acc2,
    const float* __restrict__ g2, const float* __restrict__ be2,
    const float* __restrict__ p2, const float* __restrict__ W3,
    const int* __restrict__ nodes2, int* __restrict__ nodes3,
    float* __restrict__ Y3) {
  __shared__ float sc[256]; __shared__ int si[256];
  __shared__ __align__(16) float xs[6400];
  __shared__ float sc2[64], sh2[64], cf2[64];
  __shared__ float c20s;
  const int tid = threadIdx.x, b = blockIdx.x;
  if (tid < 64) {                       // inlined fin2
    const float S = acc2[tid], Q = acc2[64 + tid];
    const float N = 51200.f;
    const float mu = S/N, var = Q/N - mu*mu, inv = rsqrtf(var + EPSF);
    const float scale = inv*g2[tid], shift = be2[tid] - mu*scale;
    const float pv = p2[tid];
    const float pn = sqrtf(wave_sum(pv*pv));
    sc2[tid] = scale; sh2[tid] = shift; cf2[tid] = scale*pv/pn;
    const float u = wave_sum(shift*pv/pn);
    if (tid == 0) c20s = u;
  }
  __syncthreads();
  const int wave = tid >> 6, lane = tid & 63;
  const float cf = cf2[lane];
  const float c20 = c20s;
  for (int i = wave; i < 200; i += 8) {
    float v = h2g[((size_t)b*200 + i)*64 + lane] * cf;
    v = wave_sum(v);
    if (lane == 0) { sc[i] = v + c20; si[i] = i; }
  }
  if (tid >= 200 && tid < 256) { sc[tid] = -INFINITY; si[tid] = 0x7fffffff; }
  bitonic_desc(sc, si, 256);
  const float scale = sc2[lane], shift = sh2[lane];
  for (int o = tid; o < 6400; o += 512) {
    const int k = o >> 6;
    const int idx = si[k];
    const float tv = tanhf(sc[k]);
    xs[o] = (h2g[((size_t)b*200 + idx)*64 + lane] * scale + shift) * tv;
  }
  for (int k = tid; k < 100; k += 512) nodes3[b*100 + k] = nodes2[b*200 + si[k]];
  __syncthreads();
  // Y3 = X3 @ W3 (unscaled; dis3 folded into conv3)
  {
    const int g = tid & 127;
    float wr[64];
    #pragma unroll
    for (int f = 0; f < 64; ++f) wr[f] = W3[f*128 + g];
    for (int o = tid; o < 12800; o += 512) {
      const int k = o >> 7;
      float acc = 0.f;
      #pragma unroll
      for (int c4 = 0; c4 < 16; ++c4) {
        const float4 x4 = *(const float4*)&xs[(k<<6) + (c4<<2)];
        acc += x4.x*wr[c4*4] + x4.y*wr[c4*4+1] + x4.z*wr[c4*4+2] + x4.w*wr[c4*4+3];
      }
      Y3[(size_t)b*12800 + o] = acc;
    }
  }
}

// ---------- K7: gather A3 + dis3 ----------
__global__ __launch_bounds__(256) void k_gatherA3(
    const float* __restrict__ data, const int* __restrict__ nodes3,
    float* __restrict__ A3, float* __restrict__ dis3) {
  __shared__ int nds[100];
  const int b = blockIdx.x / 25, rg = blockIdx.x % 25;
  const int tid = threadIdx.x;
  if (tid < 100) nds[tid] = nodes3[b*100 + tid];
  __syncthreads();
  const int wave = tid >> 6, lane = tid & 63;
  const int i = rg*4 + wave;
  const int ni = nds[i];
  const float* __restrict__ drow = data + (size_t)b*NE;
  float accd = 0.f;
  for (int j = lane; j < 100; j += 64) {
    float v = 0.f;
    if (j != i) {
      const int nj = nds[j];
      const int a = min(ni, nj), c = max(ni, nj);
      v = drow[tri_e(a, c)];
    }
    A3[((size_t)b*100 + i)*100 + j] = v;
    accd += v;
  }
  accd = wave_sum(accd);
  if (lane == 0) dis3[b*100 + i] = rsqrtf(1.f + accd);
}

// ---------- K8: conv3, lane-owns-2-features structure ----------
// grid = BB*7; block p owns rows [p*16, p*16+16). wave w owns 4 rows,
// lane = feats {lane, 64+lane}.
__global__ __launch_bounds__(256) void k_conv3(
    const float* __restrict__ A3, const float* __restrict__ Y3,
    const float* __restrict__ dis3, const float* __restrict__ b3,
    float* __restrict__ h3g, float* __restrict__ acc3g) {
  __shared__ __align__(16) float zb[25*128];  // 12.8 KB [js][feat], dis-scaled
  __shared__ __align__(16) float ab[25*16];   // 1.6 KB  [js][local row]
  __shared__ float st[256];
  const int tid = threadIdx.x;
  const int b = blockIdx.x / 7, p = blockIdx.x % 7;
  const int wave = tid >> 6, lane = tid & 63;
  const int r0 = p*16;
  st[tid] = 0.f;
  const float bl0 = b3[lane], bl1 = b3[64 + lane];
  float acc0[4] = {0,0,0,0}, acc1[4] = {0,0,0,0};
  #pragma unroll 1
  for (int s = 0; s < 4; ++s) {
    const int j0 = s*25;
    if (s) __syncthreads();
    for (int t = tid; t < 800; t += 256) {
      const int js = t >> 5, f4 = t & 31;
      const float dz = dis3[b*100 + j0 + js];
      float4 v = *(const float4*)&Y3[((size_t)b*100 + (j0 + js))*128 + (f4 << 2)];
      v.x *= dz; v.y *= dz; v.z *= dz; v.w *= dz;
      *(float4*)&zb[(js << 7) + (f4 << 2)] = v;
    }
    for (int t = tid; t < 100; t += 256) {
      const int js = t >> 2, c4 = t & 3;
      const int col = r0 + (c4 << 2);
      float4 v = make_float4(0.f, 0.f, 0.f, 0.f);
      if (col <= 96)
        v = *(const float4*)&A3[((size_t)b*100 + (j0 + js))*100 + col];
      *(float4*)&ab[(js << 4) + (c4 << 2)] = v;
    }
    __syncthreads();
    #pragma unroll 5
    for (int js = 0; js < 25; ++js) {
      const float z0 = zb[(js << 7) + lane];
      const float z1 = zb[(js << 7) + 64 + lane];
      const float4 a4 = *(const float4*)&ab[(js << 4) + (wave << 2)];
      acc0[0] += a4.x*z0; acc0[1] += a4.y*z0; acc0[2] += a4.z*z0; acc0[3] += a4.w*z0;
      acc1[0] += a4.x*z1; acc1[1] += a4.y*z1; acc1[2] += a4.z*z1; acc1[3] += a4.w*z1;
    }
  }
  float ss0 = 0.f, qq0 = 0.f, ss1 = 0.f, qq1 = 0.f;
  #pragma unroll
  for (int k = 0; k < 4; ++k) {
    const int r = r0 + (wave << 2) + k;
    if (r < 100) {
      const float d = dis3[b*100 + r];
      const float y0 = Y3[((size_t)b*100 + r)*128 + lane];
      const float y1 = Y3[((size_t)b*100 + r)*128 + 64 + lane];
      const float h0 = fmaxf(d*acc0[k] + d*d*y0 + bl0, 0.f);
      const float h1 = fmaxf(d*acc1[k] + d*d*y1 + bl1, 0.f);
      h3g[((size_t)b*100 + r)*128 + lane] = h0;
      h3g[((size_t)b*100 + r)*128 + 64 + lane] = h1;
      ss0 += h0; qq0 += h0*h0; ss1 += h1; qq1 += h1*h1;
    }
  }
  atomicAdd(&st[lane], ss0);
  atomicAdd(&st[64 + lane], ss1);
  atomicAdd(&st[128 + lane], qq0);
  atomicAdd(&st[192 + lane], qq1);
  __syncthreads();
  atomicAdd(&acc3g[tid], st[tid]);
}

// ---------- K9: inline BN-coeffs + layer-3 score + top-50 + fused max-pool ----------
__global__ __launch_bounds__(256) void k_top3(
    const float* __restrict__ h3g, const float* __restrict__ acc3,
    const float* __restrict__ g3, const float* __restrict__ be3,
    const float* __restrict__ p3, float* __restrict__ out) {
  __shared__ float sc[128]; __shared__ int si[128]; __shared__ float tv[64];
  __shared__ float scl[128], shl[128], cfl[128];
  __shared__ float red2[4];
  const int tid = threadIdx.x, b = blockIdx.x;
  const int wave = tid >> 6, lane = tid & 63;
  float scale = 0.f, shift = 0.f, pv = 0.f;
  if (tid < 128) {                      // inlined fin3
    const float S = acc3[tid], Q = acc3[128 + tid];
    const float N = 25600.f;
    const float mu = S/N, var = Q/N - mu*mu, inv = rsqrtf(var + EPSF);
    scale = inv*g3[tid]; shift = be3[tid] - mu*scale; pv = p3[tid];
    const float t2 = wave_sum(pv*pv);
    if (lane == 0) red2[wave] = t2;
  }
  __syncthreads();
  const float pn = sqrtf(red2[0] + red2[1]);
  if (tid < 128) {
    scl[tid] = scale; shl[tid] = shift; cfl[tid] = scale*pv/pn;
    const float u = wave_sum(shift*pv/pn);
    if (lane == 0) red2[2 + wave] = u;
  }
  __syncthreads();
  const float c30 = red2[2] + red2[3];
  const float clo = cfl[lane], chi = cfl[64 + lane];
  for (int i = wave; i < 100; i += 4) {
    const float* hr = h3g + ((size_t)b*100 + i)*128;
    float v = hr[lane]*clo + hr[64 + lane]*chi;
    v = wave_sum(v);
    if (lane == 0) { sc[i] = v + c30; si[i] = i; }
  }
  if (tid >= 100 && tid < 128) { sc[tid] = -INFINITY; si[tid] = 0x7fffffff; }
  bitonic_desc(sc, si, 128);
  if (tid < 50) tv[tid] = tanhf(sc[tid]);
  __syncthreads();
  if (tid < 128) {
    const float scalev = scl[tid], shiftv = shl[tid];
    float m = -INFINITY;
    for (int k = 0; k < 50; ++k) {
      const float h = h3g[((size_t)b*100 + si[k])*128 + tid];
      m = fmaxf(m, (h*scalev + shiftv)*tv[k]);
    }
    out[(size_t)b*128 + tid] = m;
  }
}

// ---------- host ----------
extern "C" void kernel_launch(void* const* d_in, const int* in_sizes, int n_in,
                              void* d_out, int out_size, void* d_ws, size_t ws_size,
                              hipStream_t stream) {
  (void)in_sizes; (void)n_in; (void)out_size; (void)ws_size;
  const float* data = (const float*)d_in[0];
  const float* W1 = (const float*)d_in[1];
  const float* b1 = (const float*)d_in[2];
  const float* g1 = (const float*)d_in[3];
  const float* be1 = (const float*)d_in[4];
  const float* p1 = (const float*)d_in[5];
  const float* W2 = (const float*)d_in[6];
  const float* b2 = (const float*)d_in[7];
  const float* g2 = (const float*)d_in[8];
  const float* be2 = (const float*)d_in[9];
  const float* p2 = (const float*)d_in[10];
  const float* W3 = (const float*)d_in[11];
  const float* b3 = (const float*)d_in[12];
  const float* g3 = (const float*)d_in[13];
  const float* be3 = (const float*)d_in[14];
  const float* p3 = (const float*)d_in[15];
  float* out = (float*)d_out;

  char* ws = (char*)d_ws;
  size_t off = 0;
  auto alloc = [&](size_t n) { size_t o = off; off += (n + 255) & ~(size_t)255; return o; };
  float* pr     = (float*)(ws + alloc((size_t)BB*49*64*4));
  float* pc     = (float*)(ws + alloc((size_t)BB*49*64*4));
  float* pr2    = (float*)(ws + alloc((size_t)BB*49*64*4));
  float* pc2    = (float*)(ws + alloc((size_t)BB*49*64*4));
  float* s1     = (float*)(ws + alloc((size_t)BB*NN0*4));
  float* accz   = (float*)(ws + alloc(448*4));   // acc1[64] | acc2[128] | acc3[256]
  int*   nodes2 = (int*)  (ws + alloc((size_t)BB*200*4));
  int*   sperm2 = (int*)  (ws + alloc((size_t)BB*200*4));
  float* Y2     = (float*)(ws + alloc((size_t)BB*12800*4));
  float* A2     = (float*)(ws + alloc((size_t)BB*40000*4));
  float* dis2   = (float*)(ws + alloc((size_t)BB*200*4));
  float* h2     = (float*)(ws + alloc((size_t)BB*12800*4));
  int*   nodes3 = (int*)  (ws + alloc((size_t)BB*100*4));
  float* Y3     = (float*)(ws + alloc((size_t)BB*12800*4));
  float* A3     = (float*)(ws + alloc((size_t)BB*10000*4));
  float* dis3   = (float*)(ws + alloc((size_t)BB*100*4));
  float* h3     = (float*)(ws + alloc((size_t)BB*12800*4));
  float* acc1 = accz;
  float* acc2 = accz + 64;
  float* acc3 = accz + 192;

  hipMemsetAsync(accz, 0, 448*4, stream);
  k_tri_mv<<<dim3(BB*7), dim3(256), 0, stream>>>(data, nullptr, nullptr, pr, pc);
  k_tri_mv<<<dim3(BB*7), dim3(256), 0, stream>>>(data, pr, pc, pr2, pc2);
  k_sfin_stats_red<<<dim3(400), dim3(256), 0, stream>>>(pr, pc, pr2, pc2, W1, b1, s1, acc1);
  k_top1<<<dim3(BB), dim3(512), 0, stream>>>(s1, acc1, W1, b1, g1, be1, p1, W2, nodes2, sperm2, Y2);
  k_gatherA2<<<dim3(BB*50), dim3(256), 0, stream>>>(data, nodes2, sperm2, A2, dis2);
  k_conv2<<<dim3(BB*7), dim3(256), 0, stream>>>(A2, Y2, dis2, b2, h2, acc2);
  k_top2<<<dim3(BB), dim3(512), 0, stream>>>(h2, acc2, g2, be2, p2, W3, nodes2, nodes3, Y3);
  k_gatherA3<<<dim3(BB*25), dim3(256), 0, stream>>>(data, nodes3, A3, dis3);
  k_conv3<<<dim3(BB*7), dim3(256), 0, stream>>>(A3, Y3, dis3, b3, h3, acc3);
  k_top3<<<dim3(BB), dim3(256), 0, stream>>>(h3, acc3, g3, be3, p3, out);
}

// Round 3
// 433.147 us; speedup vs baseline: 1.1147x; 1.1147x over previous
//
#include <hip/hip_runtime.h>
#include <math.h>

#define BB   256     // batch
#define NN0  400     // nodes at layer 1
#define NE   79800   // NN0*(NN0-1)/2
#define EPSF 1e-5f

// ---------- device helpers ----------
__device__ __forceinline__ int tri_e(int a, int c) {  // a<c, upper-tri flat index
  return a*(NN0-1) - ((a*(a-1))>>1) + (c - a - 1);
}

__device__ __forceinline__ size_t PRI(int b, int ti, int tj, int r) {
  return (((size_t)b*7 + ti)*7 + tj)*64 + r;
}

__device__ __forceinline__ float wave_sum(float v) {
  #pragma unroll
  for (int o = 32; o > 0; o >>= 1) v += __shfl_xor(v, o, 64);
  return v;
}

__device__ __forceinline__ float rdlane(float v, int k) {
  return __int_as_float(__builtin_amdgcn_readlane(__float_as_int(v), k));
}

// descending bitonic sort (score desc, idx asc == jax.lax.top_k order)
__device__ __forceinline__ void bitonic_desc(float* sc, int* si, int P) {
  const int tid = threadIdx.x;
  const int nt = blockDim.x;
  for (int k = 2; k <= P; k <<= 1) {
    for (int j = k >> 1; j > 0; j >>= 1) {
      __syncthreads();
      for (int i = tid; i < P; i += nt) {
        int ixj = i ^ j;
        if (ixj > i) {
          float a = sc[i], c = sc[ixj];
          int ai = si[i], ci = si[ixj];
          bool bef = (a > c) || (a == c && ai < ci);
          bool sw = ((i & k) == 0) ? !bef : bef;
          if (sw) { sc[i] = c; sc[ixj] = a; si[i] = ci; si[ixj] = ai; }
        }
      }
    }
  }
  __syncthreads();
}

// ---------- K1: dense symmetric tri-matvec partials (NO atomics) ----------
// XCD-swizzled: batch b lives on XCD b/32 (matches all consumers).
__global__ __launch_bounds__(256) void k_tri_mv(
    const float* __restrict__ data,
    const float* __restrict__ pr_in, const float* __restrict__ pc_in,
    float* __restrict__ pr, float* __restrict__ pc) {
  __shared__ float tile[64][65];
  __shared__ float dI[64], dJ[64];
  const int xcd = blockIdx.x & 7, slot = blockIdx.x >> 3;   // 8 x 224
  const int b = xcd*32 + slot/7, q0 = slot % 7;
  const int tid = threadIdx.x;
  const int wave = tid >> 6, lane = tid & 63;
  const float* __restrict__ drow = data + (size_t)b*NE;
  int ti_a[4], tj_a[4];
  #pragma unroll
  for (int u = 0; u < 4; ++u) {
    int t = q0 + u*7;
    int ti = 0, rem = t;
    while (rem >= 7 - ti) { rem -= 7 - ti; ++ti; }
    ti_a[u] = ti; tj_a[u] = ti + rem;
  }
  float vreg[16];
  float rI = 0.f, rJ = 0.f;
  auto issue = [&](int u) {
    const int i0 = ti_a[u]*64, j0 = tj_a[u]*64;
    const int ni = min(64, NN0 - i0), nj = min(64, NN0 - j0);
    #pragma unroll
    for (int k = 0; k < 16; ++k) {
      const int rr = wave*16 + k;
      const int i = i0 + rr, j = j0 + lane;
      vreg[k] = 0.f;
      if (rr < ni && lane < nj && j > i) vreg[k] = drow[tri_e(i, j)];
    }
    if (pr_in) {
      if (tid < 64) {
        float a = 0.f;
        if (tid < ni) {
          const int tt = ti_a[u], r = tid;
          float acc = 1.f;
          for (int tj = tt; tj < 7; ++tj) acc += pr_in[PRI(b, tt, tj, r)];
          for (int ts = 0; ts <= tt; ++ts) acc += pc_in[PRI(b, ts, tt, r)];
          a = rsqrtf(acc);
        }
        rI = a;
      } else if (tid < 128) {
        const int c = tid - 64;
        float a = 0.f;
        if (c < nj) {
          const int tt = tj_a[u], r = c;
          float acc = 1.f;
          for (int tj = tt; tj < 7; ++tj) acc += pr_in[PRI(b, tt, tj, r)];
          for (int ts = 0; ts <= tt; ++ts) acc += pc_in[PRI(b, ts, tt, r)];
          a = rsqrtf(acc);
        }
        rJ = a;
      }
    } else {
      if (tid < 64) rI = (tid < ni) ? 1.f : 0.f;
      else if (tid < 128) rJ = (tid - 64 < nj) ? 1.f : 0.f;
    }
  };
  issue(0);
  #pragma unroll 1
  for (int u = 0; u < 4; ++u) {
    const int ti = ti_a[u], tj = tj_a[u];
    if (u) __syncthreads();
    #pragma unroll
    for (int k = 0; k < 16; ++k) tile[wave*16 + k][lane] = vreg[k];
    if (tid < 64) dI[tid] = rI;
    else if (tid < 128) dJ[tid-64] = rJ;
    __syncthreads();
    if (u + 1 < 4) issue(u + 1);
    {
      const int r = tid >> 2, q = tid & 3;
      float s = 0.f;
      #pragma unroll
      for (int c = 0; c < 16; ++c) s += tile[r][q*16 + c] * dJ[q*16 + c];
      s += __shfl_xor(s, 1, 64);
      s += __shfl_xor(s, 2, 64);
      if (q == 0) pr[PRI(b, ti, tj, r)] = s;
    }
    {
      const int c = tid >> 2, q = tid & 3;
      float s = 0.f;
      #pragma unroll
      for (int r = 0; r < 16; ++r) s += tile[q*16 + r][c] * dI[q*16 + r];
      s += __shfl_xor(s, 1, 64);
      s += __shfl_xor(s, 2, 64);
      if (q == 0) pc[PRI(b, ti, tj, c)] = s;
    }
  }
}

// ---------- K2: reduce deg & s partials -> s1, + BN stats via global atomics ----------
__global__ __launch_bounds__(256) void k_sfin_stats_red(
    const float* __restrict__ pr, const float* __restrict__ pc,
    const float* __restrict__ pr2, const float* __restrict__ pc2,
    const float* __restrict__ W1, const float* __restrict__ b1,
    float* __restrict__ s1, float* __restrict__ acc1) {
  __shared__ float sl[256];
  __shared__ float st[64];
  __shared__ float w1s[32], b1s[32];
  const int tid = threadIdx.x;
  const int i = blockIdx.x*256 + tid;
  if (tid < 32) { w1s[tid] = W1[tid]; b1s[tid] = b1[tid]; }
  if (tid < 64) st[tid] = 0.f;
  const int b = i / NN0, n = i % NN0;
  const int t = n >> 6, r = n & 63;
  float dacc = 1.f, sacc = 0.f;
  for (int tj = t; tj < 7; ++tj) { dacc += pr[PRI(b, t, tj, r)]; sacc += pr2[PRI(b, t, tj, r)]; }
  for (int ti = 0; ti <= t; ++ti) { dacc += pc[PRI(b, ti, t, r)]; sacc += pc2[PRI(b, ti, t, r)]; }
  const float d = rsqrtf(dacc);
  const float s = d * (d + sacc);
  s1[i] = s;
  sl[tid] = s;
  __syncthreads();
  const int f = tid & 31, sub = tid >> 5;
  const float w = w1s[f], bb = b1s[f];
  float S = 0.f, Q = 0.f;
  #pragma unroll
  for (int k = 0; k < 32; ++k) {
    const float ss = sl[sub*32 + k];
    const float h = fmaxf(ss*w + bb, 0.f);
    S += h; Q += h*h;
  }
  atomicAdd(&st[f], S);
  atomicAdd(&st[32+f], Q);
  __syncthreads();
  if (tid < 64) atomicAdd(&acc1[tid], st[tid]);
}

// ---------- K3: inline BN-coeffs + layer-1 score + top-200 + Y2 = X2@W2 + perm ----------
__global__ __launch_bounds__(512) void k_top1(
    const float* __restrict__ s1, const float* __restrict__ acc1,
    const float* __restrict__ W1, const float* __restrict__ b1,
    const float* __restrict__ g1, const float* __restrict__ be1,
    const float* __restrict__ p1, const float* __restrict__ W2,
    int* __restrict__ nodes2, int* __restrict__ sperm2, float* __restrict__ Y2) {
  __shared__ float sc[512]; __shared__ int si[512];
  __shared__ float sS[NN0];
  __shared__ float tvs[200];
  __shared__ int nds_l[200];
  __shared__ float w1s[32], b1s[32], cfs[32], scs[32], shs[32];
  __shared__ __align__(16) float hp[6400];
  __shared__ float c0s;
  const int tid = threadIdx.x;
  const int b = (blockIdx.x & 7)*32 + (blockIdx.x >> 3);   // XCD-swizzle
  if (tid < 32) { w1s[tid] = W1[tid]; b1s[tid] = b1[tid]; }
  if (tid < 64) {                       // inlined fin1
    float scale = 0.f, shift = 0.f, pv = 0.f;
    if (tid < 32) {
      const float S = acc1[tid], Q = acc1[32 + tid];
      const float N = 102400.f;
      const float mu = S / N;
      const float var = Q / N - mu*mu;
      const float inv = rsqrtf(var + EPSF);
      scale = inv * g1[tid];
      shift = be1[tid] - mu * scale;
      pv = p1[tid];
    }
    const float pn = sqrtf(wave_sum(pv*pv));
    if (tid < 32) { scs[tid] = scale; shs[tid] = shift; cfs[tid] = scale*pv/pn; }
    float u = (tid < 32) ? shift*pv/pn : 0.f;
    u = wave_sum(u);
    if (tid == 0) c0s = u;
  }
  __syncthreads();
  const float c0 = c0s;
  {
    const int i = tid;
    if (i < NN0) {
      const float s = s1[(size_t)b*NN0 + i];
      sS[i] = s;
      float sco = c0;
      #pragma unroll
      for (int f = 0; f < 32; ++f) sco += fmaxf(s*w1s[f] + b1s[f], 0.f) * cfs[f];
      sc[i] = sco; si[i] = i;
    } else { sc[i] = -INFINITY; si[i] = 0x7fffffff; }
  }
  bitonic_desc(sc, si, 512);
  for (int k = tid; k < 200; k += 512) {
    tvs[k] = tanhf(sc[k]);
    nds_l[k] = si[k];
    nodes2[b*200 + k] = si[k];
  }
  __syncthreads();
  for (int o = tid; o < 6400; o += 512) {
    const int k = o >> 5, f = o & 31;
    const float s = sS[nds_l[k]];
    const float h = fmaxf(s*w1s[f] + b1s[f], 0.f);
    hp[o] = (h*scs[f] + shs[f]) * tvs[k];
  }
  __syncthreads();
  // Y2 = X2 @ W2 (unscaled; dis2 folded into conv2)
  {
    const int g = tid & 63;
    float wr[32];
    #pragma unroll
    for (int f = 0; f < 32; ++f) wr[f] = W2[f*64 + g];
    for (int o = tid; o < 12800; o += 512) {
      const int k = o >> 6;
      float acc = 0.f;
      #pragma unroll
      for (int c4 = 0; c4 < 8; ++c4) {
        const float4 x4 = *(const float4*)&hp[(k<<5) + (c4<<2)];
        acc += x4.x*wr[c4*4] + x4.y*wr[c4*4+1] + x4.z*wr[c4*4+2] + x4.w*wr[c4*4+3];
      }
      Y2[(size_t)b*12800 + o] = acc;
    }
  }
  __syncthreads();
  if (tid < 256) {
    sc[tid] = (tid < 200) ? -(float)nds_l[tid] : -INFINITY;
    si[tid] = (tid < 200) ? tid : 0x7fffffff;
  }
  bitonic_desc(sc, si, 256);
  if (tid < 200) sperm2[b*200 + tid] = si[tid];
}

// ---------- K4: gather A2 (sorted-id order, XCD-swizzled) + dis2 ----------
__global__ __launch_bounds__(256) void k_gatherA2(
    const float* __restrict__ data, const int* __restrict__ nodes2,
    const int* __restrict__ sperm2, float* __restrict__ A2, float* __restrict__ dis2) {
  __shared__ int nds[200], sp[200], sn[200];
  __shared__ float rowbuf[4][200];
  const int idx = blockIdx.x;
  const int r9 = idx >> 3;
  const int b = (idx & 7)*32 + r9/50;
  const int rg = r9 % 50;
  const int tid = threadIdx.x;
  if (tid < 200) { nds[tid] = nodes2[b*200 + tid]; sp[tid] = sperm2[b*200 + tid]; }
  __syncthreads();
  if (tid < 200) sn[tid] = nds[sp[tid]];
  __syncthreads();
  const int wave = tid >> 6, lane = tid & 63;
  const int i = rg*4 + wave;
  const int ni = nds[i];
  const float* __restrict__ drow = data + (size_t)b*NE;
  float accd = 0.f;
  for (int jj = lane; jj < 200; jj += 64) {
    const int sj = sn[jj];
    float v = 0.f;
    if (sj != ni) {
      const int a = min(ni, sj), c = max(ni, sj);
      v = drow[tri_e(a, c)];
    }
    rowbuf[wave][sp[jj]] = v;
    accd += v;
  }
  __syncthreads();
  for (int j = lane; j < 200; j += 64)
    A2[((size_t)b*200 + i)*200 + j] = rowbuf[wave][j];
  accd = wave_sum(accd);
  if (lane == 0) dis2[b*200 + i] = rsqrtf(1.f + accd);
}

// ---------- K5: conv2 via readlane broadcast (VALU-bound) ----------
// grid = BB*2 (XCD-swizzled). Block p owns rows [p*100, p*100+100);
// wave w owns 25 rows, lane = feature. Per j: 1 ds_read_b32 (z) +
// 1 masked global load (A row frag) + 25 x {v_readlane + v_fmac}.
__global__ __launch_bounds__(256) void k_conv2(
    const float* __restrict__ A2, const float* __restrict__ Y2,
    const float* __restrict__ dis2, const float* __restrict__ b2,
    float* __restrict__ h2g, float* __restrict__ acc2g) {
  __shared__ __align__(16) float zb[200*64];   // 51.2 KB, dis-scaled Y2
  __shared__ float dsb[200];
  __shared__ float st[128];
  const int tid = threadIdx.x;
  const int xcd = blockIdx.x & 7, slot = blockIdx.x >> 3;   // 8 x 64
  const int b = xcd*32 + (slot >> 1), p = slot & 1;
  const int wave = tid >> 6, lane = tid & 63;
  if (tid < 128) st[tid] = 0.f;
  if (tid < 200) dsb[tid] = dis2[b*200 + tid];
  for (int t = tid; t < 3200; t += 256) {
    const int row = t >> 4, f4 = t & 15;
    const float dz = dis2[b*200 + row];
    float4 v = *(const float4*)&Y2[((size_t)b*200 + row)*64 + (f4 << 2)];
    v.x *= dz; v.y *= dz; v.z *= dz; v.w *= dz;
    *(float4*)&zb[(row << 6) + (f4 << 2)] = v;
  }
  const float bl = b2[lane];
  __syncthreads();
  const int rb = p*100 + wave*25;
  auto ldA = [&](int j) -> float {
    return (lane < 25) ? A2[((size_t)b*200 + j)*200 + rb + lane] : 0.f;
  };
  float acc[25];
  #pragma unroll
  for (int k = 0; k < 25; ++k) acc[k] = 0.f;
  float a_cur = ldA(0);
  #pragma unroll 2
  for (int j = 0; j < 200; ++j) {
    const float a_nxt = (j < 199) ? ldA(j + 1) : 0.f;
    const float z = zb[(j << 6) + lane];
    #pragma unroll
    for (int k = 0; k < 25; ++k)
      acc[k] = fmaf(rdlane(a_cur, k), z, acc[k]);
    a_cur = a_nxt;
  }
  float ss = 0.f, qq = 0.f;
  #pragma unroll
  for (int k = 0; k < 25; ++k) {
    const int r = rb + k;
    const float d = dsb[r];
    const float h = fmaxf(d*(acc[k] + zb[(r << 6) + lane]) + bl, 0.f);
    h2g[((size_t)b*200 + r)*64 + lane] = h;
    ss += h; qq += h*h;
  }
  atomicAdd(&st[lane], ss);
  atomicAdd(&st[64 + lane], qq);
  __syncthreads();
  if (tid < 128) atomicAdd(&acc2g[tid], st[tid]);
}

// ---------- K6: inline BN-coeffs + layer-2 score + top-100 + Y3 = X3@W3 ----------
__global__ __launch_bounds__(512) void k_top2(
    const float* __restrict__ h2g, const float* __restrict__ acc2,
    const float* __restrict__ g2, const float* __restrict__ be2,
    const float* __restrict__ p2, const float* __restrict__ W3,
    const int* __restrict__ nodes2, int* __restrict__ nodes3,
    float* __restrict__ Y3) {
  __shared__ float sc[256]; __shared__ int si[256];
  __shared__ __align__(16) float xs[6400];
  __shared__ float sc2[64], sh2[64], cf2[64];
  __shared__ float c20s;
  const int tid = threadIdx.x;
  const int b = (blockIdx.x & 7)*32 + (blockIdx.x >> 3);   // XCD-swizzle
  if (tid < 64) {                       // inlined fin2
    const float S = acc2[tid], Q = acc2[64 + tid];
    const float N = 51200.f;
    const float mu = S/N, var = Q/N - mu*mu, inv = rsqrtf(var + EPSF);
    const float scale = inv*g2[tid], shift = be2[tid] - mu*scale;
    const float pv = p2[tid];
    const float pn = sqrtf(wave_sum(pv*pv));
    sc2[tid] = scale; sh2[tid] = shift; cf2[tid] = scale*pv/pn;
    const float u = wave_sum(shift*pv/pn);
    if (tid == 0) c20s = u;
  }
  __syncthreads();
  const int wave = tid >> 6, lane = tid & 63;
  const float cf = cf2[lane];
  const float c20 = c20s;
  for (int i = wave; i < 200; i += 8) {
    float v = h2g[((size_t)b*200 + i)*64 + lane] * cf;
    v = wave_sum(v);
    if (lane == 0) { sc[i] = v + c20; si[i] = i; }
  }
  if (tid >= 200 && tid < 256) { sc[tid] = -INFINITY; si[tid] = 0x7fffffff; }
  bitonic_desc(sc, si, 256);
  const float scale = sc2[lane], shift = sh2[lane];
  for (int o = tid; o < 6400; o += 512) {
    const int k = o >> 6;
    const int idx = si[k];
    const float tv = tanhf(sc[k]);
    xs[o] = (h2g[((size_t)b*200 + idx)*64 + lane] * scale + shift) * tv;
  }
  for (int k = tid; k < 100; k += 512) nodes3[b*100 + k] = nodes2[b*200 + si[k]];
  __syncthreads();
  // Y3 = X3 @ W3 (unscaled; dis3 folded into conv3)
  {
    const int g = tid & 127;
    float wr[64];
    #pragma unroll
    for (int f = 0; f < 64; ++f) wr[f] = W3[f*128 + g];
    for (int o = tid; o < 12800; o += 512) {
      const int k = o >> 7;
      float acc = 0.f;
      #pragma unroll
      for (int c4 = 0; c4 < 16; ++c4) {
        const float4 x4 = *(const float4*)&xs[(k<<6) + (c4<<2)];
        acc += x4.x*wr[c4*4] + x4.y*wr[c4*4+1] + x4.z*wr[c4*4+2] + x4.w*wr[c4*4+3];
      }
      Y3[(size_t)b*12800 + o] = acc;
    }
  }
}

// ---------- K7: gather A3 + dis3 (XCD-swizzled) ----------
__global__ __launch_bounds__(256) void k_gatherA3(
    const float* __restrict__ data, const int* __restrict__ nodes3,
    float* __restrict__ A3, float* __restrict__ dis3) {
  __shared__ int nds[100];
  const int slot = blockIdx.x >> 3;                 // 8 x 800
  const int b = (blockIdx.x & 7)*32 + slot/25, rg = slot % 25;
  const int tid = threadIdx.x;
  if (tid < 100) nds[tid] = nodes3[b*100 + tid];
  __syncthreads();
  const int wave = tid >> 6, lane = tid & 63;
  const int i = rg*4 + wave;
  const int ni = nds[i];
  const float* __restrict__ drow = data + (size_t)b*NE;
  float accd = 0.f;
  for (int j = lane; j < 100; j += 64) {
    float v = 0.f;
    if (j != i) {
      const int nj = nds[j];
      const int a = min(ni, nj), c = max(ni, nj);
      v = drow[tri_e(a, c)];
    }
    A3[((size_t)b*100 + i)*100 + j] = v;
    accd += v;
  }
  accd = wave_sum(accd);
  if (lane == 0) dis3[b*100 + i] = rsqrtf(1.f + accd);
}

// ---------- K8: conv3 via readlane broadcast (lane owns 2 feats) ----------
// grid = BB*2 (XCD-swizzled). Block p owns rows [p*50, p*50+50);
// wave w owns up to 13 rows (4*13=52 slots, 50 valid). Per j:
// 2 ds_read_b32 (z0,z1) + 1 masked global (A frag) + 13 readlane + 26 fmac.
__global__ __launch_bounds__(256) void k_conv3(
    const float* __restrict__ A3, const float* __restrict__ Y3,
    const float* __restrict__ dis3, const float* __restrict__ b3,
    float* __restrict__ h3g, float* __restrict__ acc3g) {
  __shared__ __align__(16) float zb[100*128];  // 51.2 KB, dis-scaled Y3
  __shared__ float dsb[100];
  __shared__ float st[256];
  const int tid = threadIdx.x;
  const int xcd = blockIdx.x & 7, slot = blockIdx.x >> 3;   // 8 x 64
  const int b = xcd*32 + (slot >> 1), p = slot & 1;
  const int wave = tid >> 6, lane = tid & 63;
  st[tid] = 0.f;
  if (tid < 100) dsb[tid] = dis3[b*100 + tid];
  for (int t = tid; t < 3200; t += 256) {
    const int row = t >> 5, f4 = t & 31;
    const float dz = dis3[b*100 + row];
    float4 v = *(const float4*)&Y3[((size_t)b*100 + row)*128 + (f4 << 2)];
    v.x *= dz; v.y *= dz; v.z *= dz; v.w *= dz;
    *(float4*)&zb[(row << 7) + (f4 << 2)] = v;
  }
  const float bl0 = b3[lane], bl1 = b3[64 + lane];
  __syncthreads();
  const int rb = p*50;
  const int lw = wave*13;
  auto ldA = [&](int j) -> float {
    return (lane < 13 && lw + lane < 50)
      ? A3[((size_t)b*100 + j)*100 + rb + lw + lane] : 0.f;
  };
  float acc0[13], acc1[13];
  #pragma unroll
  for (int k = 0; k < 13; ++k) { acc0[k] = 0.f; acc1[k] = 0.f; }
  float a_cur = ldA(0);
  #pragma unroll 2
  for (int j = 0; j < 100; ++j) {
    const float a_nxt = (j < 99) ? ldA(j + 1) : 0.f;
    const float z0 = zb[(j << 7) + lane];
    const float z1 = zb[(j << 7) + 64 + lane];
    #pragma unroll
    for (int k = 0; k < 13; ++k) {
      const float av = rdlane(a_cur, k);
      acc0[k] = fmaf(av, z0, acc0[k]);
      acc1[k] = fmaf(av, z1, acc1[k]);
    }
    a_cur = a_nxt;
  }
  float ss0 = 0.f, qq0 = 0.f, ss1 = 0.f, qq1 = 0.f;
  #pragma unroll
  for (int k = 0; k < 13; ++k) {
    const int lr = lw + k;
    if (lr < 50) {
      const int r = rb + lr;
      const float d = dsb[r];
      const float h0 = fmaxf(d*(acc0[k] + zb[(r << 7) + lane]) + bl0, 0.f);
      const float h1 = fmaxf(d*(acc1[k] + zb[(r << 7) + 64 + lane]) + bl1, 0.f);
      h3g[((size_t)b*100 + r)*128 + lane] = h0;
      h3g[((size_t)b*100 + r)*128 + 64 + lane] = h1;
      ss0 += h0; qq0 += h0*h0; ss1 += h1; qq1 += h1*h1;
    }
  }
  atomicAdd(&st[lane], ss0);
  atomicAdd(&st[64 + lane], ss1);
  atomicAdd(&st[128 + lane], qq0);
  atomicAdd(&st[192 + lane], qq1);
  __syncthreads();
  atomicAdd(&acc3g[tid], st[tid]);
}

// ---------- K9: inline BN-coeffs + layer-3 score + top-50 + fused max-pool ----------
__global__ __launch_bounds__(256) void k_top3(
    const float* __restrict__ h3g, const float* __restrict__ acc3,
    const float* __restrict__ g3, const float* __restrict__ be3,
    const float* __restrict__ p3, float* __restrict__ out) {
  __shared__ float sc[128]; __shared__ int si[128]; __shared__ float tv[64];
  __shared__ float scl[128], shl[128], cfl[128];
  __shared__ float red2[4];
  const int tid = threadIdx.x;
  const int b = (blockIdx.x & 7)*32 + (blockIdx.x >> 3);   // XCD-swizzle
  const int wave = tid >> 6, lane = tid & 63;
  float scale = 0.f, shift = 0.f, pv = 0.f;
  if (tid < 128) {                      // inlined fin3
    const float S = acc3[tid], Q = acc3[128 + tid];
    const float N = 25600.f;
    const float mu = S/N, var = Q/N - mu*mu, inv = rsqrtf(var + EPSF);
    scale = inv*g3[tid]; shift = be3[tid] - mu*scale; pv = p3[tid];
    const float t2 = wave_sum(pv*pv);
    if (lane == 0) red2[wave] = t2;
  }
  __syncthreads();
  const float pn = sqrtf(red2[0] + red2[1]);
  if (tid < 128) {
    scl[tid] = scale; shl[tid] = shift; cfl[tid] = scale*pv/pn;
    const float u = wave_sum(shift*pv/pn);
    if (lane == 0) red2[2 + wave] = u;
  }
  __syncthreads();
  const float c30 = red2[2] + red2[3];
  const float clo = cfl[lane], chi = cfl[64 + lane];
  for (int i = wave; i < 100; i += 4) {
    const float* hr = h3g + ((size_t)b*100 + i)*128;
    float v = hr[lane]*clo + hr[64 + lane]*chi;
    v = wave_sum(v);
    if (lane == 0) { sc[i] = v + c30; si[i] = i; }
  }
  if (tid >= 100 && tid < 128) { sc[tid] = -INFINITY; si[tid] = 0x7fffffff; }
  bitonic_desc(sc, si, 128);
  if (tid < 50) tv[tid] = tanhf(sc[tid]);
  __syncthreads();
  if (tid < 128) {
    const float scalev = scl[tid], shiftv = shl[tid];
    float m = -INFINITY;
    for (int k = 0; k < 50; ++k) {
      const float h = h3g[((size_t)b*100 + si[k])*128 + tid];
      m = fmaxf(m, (h*scalev + shiftv)*tv[k]);
    }
    out[(size_t)b*128 + tid] = m;
  }
}

// ---------- host ----------
extern "C" void kernel_launch(void* const* d_in, const int* in_sizes, int n_in,
                              void* d_out, int out_size, void* d_ws, size_t ws_size,
                              hipStream_t stream) {
  (void)in_sizes; (void)n_in; (void)out_size; (void)ws_size;
  const float* data = (const float*)d_in[0];
  const float* W1 = (const float*)d_in[1];
  const float* b1 = (const float*)d_in[2];
  const float* g1 = (const float*)d_in[3];
  const float* be1 = (const float*)d_in[4];
  const float* p1 = (const float*)d_in[5];
  const float* W2 = (const float*)d_in[6];
  const float* b2 = (const float*)d_in[7];
  const float* g2 = (const float*)d_in[8];
  const float* be2 = (const float*)d_in[9];
  const float* p2 = (const float*)d_in[10];
  const float* W3 = (const float*)d_in[11];
  const float* b3 = (const float*)d_in[12];
  const float* g3 = (const float*)d_in[13];
  const float* be3 = (const float*)d_in[14];
  const float* p3 = (const float*)d_in[15];
  float* out = (float*)d_out;

  char* ws = (char*)d_ws;
  size_t off = 0;
  auto alloc = [&](size_t n) { size_t o = off; off += (n + 255) & ~(size_t)255; return o; };
  float* pr     = (float*)(ws + alloc((size_t)BB*49*64*4));
  float* pc     = (float*)(ws + alloc((size_t)BB*49*64*4));
  float* pr2    = (float*)(ws + alloc((size_t)BB*49*64*4));
  float* pc2    = (float*)(ws + alloc((size_t)BB*49*64*4));
  float* s1     = (float*)(ws + alloc((size_t)BB*NN0*4));
  float* accz   = (float*)(ws + alloc(448*4));   // acc1[64] | acc2[128] | acc3[256]
  int*   nodes2 = (int*)  (ws + alloc((size_t)BB*200*4));
  int*   sperm2 = (int*)  (ws + alloc((size_t)BB*200*4));
  float* Y2     = (float*)(ws + alloc((size_t)BB*12800*4));
  float* A2     = (float*)(ws + alloc((size_t)BB*40000*4));
  float* dis2   = (float*)(ws + alloc((size_t)BB*200*4));
  float* h2     = (float*)(ws + alloc((size_t)BB*12800*4));
  int*   nodes3 = (int*)  (ws + alloc((size_t)BB*100*4));
  float* Y3     = (float*)(ws + alloc((size_t)BB*12800*4));
  float* A3     = (float*)(ws + alloc((size_t)BB*10000*4));
  float* dis3   = (float*)(ws + alloc((size_t)BB*100*4));
  float* h3     = (float*)(ws + alloc((size_t)BB*12800*4));
  float* acc1 = accz;
  float* acc2 = accz + 64;
  float* acc3 = accz + 192;

  hipMemsetAsync(accz, 0, 448*4, stream);
  k_tri_mv<<<dim3(BB*7), dim3(256), 0, stream>>>(data, nullptr, nullptr, pr, pc);
  k_tri_mv<<<dim3(BB*7), dim3(256), 0, stream>>>(data, pr, pc, pr2, pc2);
  k_sfin_stats_red<<<dim3(400), dim3(256), 0, stream>>>(pr, pc, pr2, pc2, W1, b1, s1, acc1);
  k_top1<<<dim3(BB), dim3(512), 0, stream>>>(s1, acc1, W1, b1, g1, be1, p1, W2, nodes2, sperm2, Y2);
  k_gatherA2<<<dim3(BB*50), dim3(256), 0, stream>>>(data, nodes2, sperm2, A2, dis2);
  k_conv2<<<dim3(BB*2), dim3(256), 0, stream>>>(A2, Y2, dis2, b2, h2, acc2);
  k_top2<<<dim3(BB), dim3(512), 0, stream>>>(h2, acc2, g2, be2, p2, W3, nodes2, nodes3, Y3);
  k_gatherA3<<<dim3(BB*25), dim3(256), 0, stream>>>(data, nodes3, A3, dis3);
  k_conv3<<<dim3(BB*2), dim3(256), 0, stream>>>(A3, Y3, dis3, b3, h3, acc3);
  k_top3<<<dim3(BB), dim3(256), 0, stream>>>(h3, acc3, g3, be3, p3, out);
}

// Round 4
// 427.258 us; speedup vs baseline: 1.1300x; 1.0138x over previous
//
#include <hip/hip_runtime.h>
#include <math.h>

#define BB   256     // batch
#define NN0  400     // nodes at layer 1
#define NE   79800   // NN0*(NN0-1)/2
#define EPSF 1e-5f

// ---------- device helpers ----------
__device__ __forceinline__ int tri_e(int a, int c) {  // a<c, upper-tri flat index
  return a*(NN0-1) - ((a*(a-1))>>1) + (c - a - 1);
}

__device__ __forceinline__ size_t PRI(int b, int ti, int tj, int r) {
  return (((size_t)b*7 + ti)*7 + tj)*64 + r;
}

__device__ __forceinline__ float wave_sum(float v) {
  #pragma unroll
  for (int o = 32; o > 0; o >>= 1) v += __shfl_xor(v, o, 64);
  return v;
}

__device__ __forceinline__ float rdlane(float v, int k) {
  return __int_as_float(__builtin_amdgcn_readlane(__float_as_int(v), k));
}

// descending bitonic sort (score desc, idx asc == jax.lax.top_k order)
__device__ __forceinline__ void bitonic_desc(float* sc, int* si, int P) {
  const int tid = threadIdx.x;
  const int nt = blockDim.x;
  for (int k = 2; k <= P; k <<= 1) {
    for (int j = k >> 1; j > 0; j >>= 1) {
      __syncthreads();
      for (int i = tid; i < P; i += nt) {
        int ixj = i ^ j;
        if (ixj > i) {
          float a = sc[i], c = sc[ixj];
          int ai = si[i], ci = si[ixj];
          bool bef = (a > c) || (a == c && ai < ci);
          bool sw = ((i & k) == 0) ? !bef : bef;
          if (sw) { sc[i] = c; sc[ixj] = a; si[i] = ci; si[ixj] = ai; }
        }
      }
    }
  }
  __syncthreads();
}

// ---------- K1: dense symmetric tri-matvec partials (NO atomics) ----------
// XCD-swizzled: batch b lives on XCD b/32 (matches all consumers).
__global__ __launch_bounds__(256) void k_tri_mv(
    const float* __restrict__ data,
    const float* __restrict__ pr_in, const float* __restrict__ pc_in,
    float* __restrict__ pr, float* __restrict__ pc) {
  __shared__ float tile[64][65];
  __shared__ float dI[64], dJ[64];
  const int xcd = blockIdx.x & 7, slot = blockIdx.x >> 3;   // 8 x 224
  const int b = xcd*32 + slot/7, q0 = slot % 7;
  const int tid = threadIdx.x;
  const int wave = tid >> 6, lane = tid & 63;
  const float* __restrict__ drow = data + (size_t)b*NE;
  int ti_a[4], tj_a[4];
  #pragma unroll
  for (int u = 0; u < 4; ++u) {
    int t = q0 + u*7;
    int ti = 0, rem = t;
    while (rem >= 7 - ti) { rem -= 7 - ti; ++ti; }
    ti_a[u] = ti; tj_a[u] = ti + rem;
  }
  float vreg[16];
  float rI = 0.f, rJ = 0.f;
  auto issue = [&](int u) {
    const int i0 = ti_a[u]*64, j0 = tj_a[u]*64;
    const int ni = min(64, NN0 - i0), nj = min(64, NN0 - j0);
    #pragma unroll
    for (int k = 0; k < 16; ++k) {
      const int rr = wave*16 + k;
      const int i = i0 + rr, j = j0 + lane;
      vreg[k] = 0.f;
      if (rr < ni && lane < nj && j > i) vreg[k] = drow[tri_e(i, j)];
    }
    if (pr_in) {
      if (tid < 64) {
        float a = 0.f;
        if (tid < ni) {
          const int tt = ti_a[u], r = tid;
          float acc = 1.f;
          for (int tj = tt; tj < 7; ++tj) acc += pr_in[PRI(b, tt, tj, r)];
          for (int ts = 0; ts <= tt; ++ts) acc += pc_in[PRI(b, ts, tt, r)];
          a = rsqrtf(acc);
        }
        rI = a;
      } else if (tid < 128) {
        const int c = tid - 64;
        float a = 0.f;
        if (c < nj) {
          const int tt = tj_a[u], r = c;
          float acc = 1.f;
          for (int tj = tt; tj < 7; ++tj) acc += pr_in[PRI(b, tt, tj, r)];
          for (int ts = 0; ts <= tt; ++ts) acc += pc_in[PRI(b, ts, tt, r)];
          a = rsqrtf(acc);
        }
        rJ = a;
      }
    } else {
      if (tid < 64) rI = (tid < ni) ? 1.f : 0.f;
      else if (tid < 128) rJ = (tid - 64 < nj) ? 1.f : 0.f;
    }
  };
  issue(0);
  #pragma unroll 1
  for (int u = 0; u < 4; ++u) {
    const int ti = ti_a[u], tj = tj_a[u];
    if (u) __syncthreads();
    #pragma unroll
    for (int k = 0; k < 16; ++k) tile[wave*16 + k][lane] = vreg[k];
    if (tid < 64) dI[tid] = rI;
    else if (tid < 128) dJ[tid-64] = rJ;
    __syncthreads();
    if (u + 1 < 4) issue(u + 1);
    {
      const int r = tid >> 2, q = tid & 3;
      float s = 0.f;
      #pragma unroll
      for (int c = 0; c < 16; ++c) s += tile[r][q*16 + c] * dJ[q*16 + c];
      s += __shfl_xor(s, 1, 64);
      s += __shfl_xor(s, 2, 64);
      if (q == 0) pr[PRI(b, ti, tj, r)] = s;
    }
    {
      const int c = tid >> 2, q = tid & 3;
      float s = 0.f;
      #pragma unroll
      for (int r = 0; r < 16; ++r) s += tile[q*16 + r][c] * dI[q*16 + r];
      s += __shfl_xor(s, 1, 64);
      s += __shfl_xor(s, 2, 64);
      if (q == 0) pc[PRI(b, ti, tj, c)] = s;
    }
  }
}

// ---------- K2: reduce deg & s partials -> s1, + BN stats via global atomics ----------
__global__ __launch_bounds__(256) void k_sfin_stats_red(
    const float* __restrict__ pr, const float* __restrict__ pc,
    const float* __restrict__ pr2, const float* __restrict__ pc2,
    const float* __restrict__ W1, const float* __restrict__ b1,
    float* __restrict__ s1, float* __restrict__ acc1) {
  __shared__ float sl[256];
  __shared__ float st[64];
  __shared__ float w1s[32], b1s[32];
  const int tid = threadIdx.x;
  const int i = blockIdx.x*256 + tid;
  if (tid < 32) { w1s[tid] = W1[tid]; b1s[tid] = b1[tid]; }
  if (tid < 64) st[tid] = 0.f;
  const int b = i / NN0, n = i % NN0;
  const int t = n >> 6, r = n & 63;
  float dacc = 1.f, sacc = 0.f;
  for (int tj = t; tj < 7; ++tj) { dacc += pr[PRI(b, t, tj, r)]; sacc += pr2[PRI(b, t, tj, r)]; }
  for (int ti = 0; ti <= t; ++ti) { dacc += pc[PRI(b, ti, t, r)]; sacc += pc2[PRI(b, ti, t, r)]; }
  const float d = rsqrtf(dacc);
  const float s = d * (d + sacc);
  s1[i] = s;
  sl[tid] = s;
  __syncthreads();
  const int f = tid & 31, sub = tid >> 5;
  const float w = w1s[f], bb = b1s[f];
  float S = 0.f, Q = 0.f;
  #pragma unroll
  for (int k = 0; k < 32; ++k) {
    const float ss = sl[sub*32 + k];
    const float h = fmaxf(ss*w + bb, 0.f);
    S += h; Q += h*h;
  }
  atomicAdd(&st[f], S);
  atomicAdd(&st[32+f], Q);
  __syncthreads();
  if (tid < 64) atomicAdd(&acc1[tid], st[tid]);
}

// ---------- K3: inline BN-coeffs + layer-1 score + top-200 + Y2 = X2@W2 + perm ----------
__global__ __launch_bounds__(512) void k_top1(
    const float* __restrict__ s1, const float* __restrict__ acc1,
    const float* __restrict__ W1, const float* __restrict__ b1,
    const float* __restrict__ g1, const float* __restrict__ be1,
    const float* __restrict__ p1, const float* __restrict__ W2,
    int* __restrict__ nodes2, int* __restrict__ sperm2, float* __restrict__ Y2) {
  __shared__ float sc[512]; __shared__ int si[512];
  __shared__ float sS[NN0];
  __shared__ float tvs[200];
  __shared__ int nds_l[200];
  __shared__ float w1s[32], b1s[32], cfs[32], scs[32], shs[32];
  __shared__ __align__(16) float hp[6400];
  __shared__ float c0s;
  const int tid = threadIdx.x;
  const int b = (blockIdx.x & 7)*32 + (blockIdx.x >> 3);   // XCD-swizzle
  if (tid < 32) { w1s[tid] = W1[tid]; b1s[tid] = b1[tid]; }
  if (tid < 64) {                       // inlined fin1
    float scale = 0.f, shift = 0.f, pv = 0.f;
    if (tid < 32) {
      const float S = acc1[tid], Q = acc1[32 + tid];
      const float N = 102400.f;
      const float mu = S / N;
      const float var = Q / N - mu*mu;
      const float inv = rsqrtf(var + EPSF);
      scale = inv * g1[tid];
      shift = be1[tid] - mu * scale;
      pv = p1[tid];
    }
    const float pn = sqrtf(wave_sum(pv*pv));
    if (tid < 32) { scs[tid] = scale; shs[tid] = shift; cfs[tid] = scale*pv/pn; }
    float u = (tid < 32) ? shift*pv/pn : 0.f;
    u = wave_sum(u);
    if (tid == 0) c0s = u;
  }
  __syncthreads();
  const float c0 = c0s;
  {
    const int i = tid;
    if (i < NN0) {
      const float s = s1[(size_t)b*NN0 + i];
      sS[i] = s;
      float sco = c0;
      #pragma unroll
      for (int f = 0; f < 32; ++f) sco += fmaxf(s*w1s[f] + b1s[f], 0.f) * cfs[f];
      sc[i] = sco; si[i] = i;
    } else { sc[i] = -INFINITY; si[i] = 0x7fffffff; }
  }
  bitonic_desc(sc, si, 512);
  for (int k = tid; k < 200; k += 512) {
    tvs[k] = tanhf(sc[k]);
    nds_l[k] = si[k];
    nodes2[b*200 + k] = si[k];
  }
  __syncthreads();
  for (int o = tid; o < 6400; o += 512) {
    const int k = o >> 5, f = o & 31;
    const float s = sS[nds_l[k]];
    const float h = fmaxf(s*w1s[f] + b1s[f], 0.f);
    hp[o] = (h*scs[f] + shs[f]) * tvs[k];
  }
  __syncthreads();
  // Y2 = X2 @ W2 (unscaled; dis2 folded into conv2)
  {
    const int g = tid & 63;
    float wr[32];
    #pragma unroll
    for (int f = 0; f < 32; ++f) wr[f] = W2[f*64 + g];
    for (int o = tid; o < 12800; o += 512) {
      const int k = o >> 6;
      float acc = 0.f;
      #pragma unroll
      for (int c4 = 0; c4 < 8; ++c4) {
        const float4 x4 = *(const float4*)&hp[(k<<5) + (c4<<2)];
        acc += x4.x*wr[c4*4] + x4.y*wr[c4*4+1] + x4.z*wr[c4*4+2] + x4.w*wr[c4*4+3];
      }
      Y2[(size_t)b*12800 + o] = acc;
    }
  }
  __syncthreads();
  if (tid < 256) {
    sc[tid] = (tid < 200) ? -(float)nds_l[tid] : -INFINITY;
    si[tid] = (tid < 200) ? tid : 0x7fffffff;
  }
  bitonic_desc(sc, si, 256);
  if (tid < 200) sperm2[b*200 + tid] = si[tid];
}

// ---------- K4: gather A2 (sorted-id order, XCD-swizzled) + dis2 ----------
__global__ __launch_bounds__(256) void k_gatherA2(
    const float* __restrict__ data, const int* __restrict__ nodes2,
    const int* __restrict__ sperm2, float* __restrict__ A2, float* __restrict__ dis2) {
  __shared__ int nds[200], sp[200], sn[200];
  __shared__ float rowbuf[4][200];
  const int idx = blockIdx.x;
  const int r9 = idx >> 3;
  const int b = (idx & 7)*32 + r9/50;
  const int rg = r9 % 50;
  const int tid = threadIdx.x;
  if (tid < 200) { nds[tid] = nodes2[b*200 + tid]; sp[tid] = sperm2[b*200 + tid]; }
  __syncthreads();
  if (tid < 200) sn[tid] = nds[sp[tid]];
  __syncthreads();
  const int wave = tid >> 6, lane = tid & 63;
  const int i = rg*4 + wave;
  const int ni = nds[i];
  const float* __restrict__ drow = data + (size_t)b*NE;
  float accd = 0.f;
  for (int jj = lane; jj < 200; jj += 64) {
    const int sj = sn[jj];
    float v = 0.f;
    if (sj != ni) {
      const int a = min(ni, sj), c = max(ni, sj);
      v = drow[tri_e(a, c)];
    }
    rowbuf[wave][sp[jj]] = v;
    accd += v;
  }
  __syncthreads();
  for (int j = lane; j < 200; j += 64)
    A2[((size_t)b*200 + i)*200 + j] = rowbuf[wave][j];
  accd = wave_sum(accd);
  if (lane == 0) dis2[b*200 + i] = rsqrtf(1.f + accd);
}

// ---------- K5: conv2 via readlane broadcast, 2-j packed loads, 4-deep ring ----------
// grid = BB*2 (XCD-swizzled). Block p owns rows [p*100, p*100+100);
// wave w owns 25 rows, lane = feature. A-loads: lanes 0..49 carry 2 j's
// (q = lane/25, k = lane%25), ring of 4 loads -> 8 j's in flight.
__global__ __launch_bounds__(256) void k_conv2(
    const float* __restrict__ A2, const float* __restrict__ Y2,
    const float* __restrict__ dis2, const float* __restrict__ b2,
    float* __restrict__ h2g, float* __restrict__ acc2g) {
  __shared__ __align__(16) float zb[200*64];   // 51.2 KB, dis-scaled Y2
  __shared__ float dsb[200];
  __shared__ float st[128];
  const int tid = threadIdx.x;
  const int xcd = blockIdx.x & 7, slot = blockIdx.x >> 3;   // 8 x 64
  const int b = xcd*32 + (slot >> 1), p = slot & 1;
  const int wave = tid >> 6, lane = tid & 63;
  if (tid < 128) st[tid] = 0.f;
  if (tid < 200) dsb[tid] = dis2[b*200 + tid];
  for (int t = tid; t < 3200; t += 256) {
    const int row = t >> 4, f4 = t & 15;
    const float dz = dis2[b*200 + row];
    float4 v = *(const float4*)&Y2[((size_t)b*200 + row)*64 + (f4 << 2)];
    v.x *= dz; v.y *= dz; v.z *= dz; v.w *= dz;
    *(float4*)&zb[(row << 6) + (f4 << 2)] = v;
  }
  const float bl = b2[lane];
  __syncthreads();
  const int rb = p*100 + wave*25;
  const int lq = (lane >= 25) ? 1 : 0;          // sub-j within packed load
  const int lk = lane - lq*25;                  // row index within wave
  const bool lv = (lane < 50);
  // packed load: lanes 0..24 -> A[j][rb+k], lanes 25..49 -> A[j+1][rb+k]
  auto ldA = [&](int j) -> float {
    return lv ? A2[((size_t)b*200 + j + lq)*200 + rb + lk] : 0.f;
  };
  float acc[25];
  #pragma unroll
  for (int k = 0; k < 25; ++k) acc[k] = 0.f;
  float abuf[4];
  #pragma unroll
  for (int i = 0; i < 4; ++i) abuf[i] = ldA(2*i);
  #pragma unroll 2
  for (int jp = 0; jp < 100; ++jp) {
    const int j = jp << 1;
    float a;
    switch (jp & 3) {                 // static ring indexing (no scratch)
      case 0: a = abuf[0]; if (jp + 4 < 100) abuf[0] = ldA(j + 8); break;
      case 1: a = abuf[1]; if (jp + 4 < 100) abuf[1] = ldA(j + 8); break;
      case 2: a = abuf[2]; if (jp + 4 < 100) abuf[2] = ldA(j + 8); break;
      default: a = abuf[3]; if (jp + 4 < 100) abuf[3] = ldA(j + 8); break;
    }
    const float z0 = zb[(j << 6) + lane];
    const float z1 = zb[((j + 1) << 6) + lane];
    #pragma unroll
    for (int k = 0; k < 25; ++k)
      acc[k] = fmaf(rdlane(a, k), z0, acc[k]);
    #pragma unroll
    for (int k = 0; k < 25; ++k)
      acc[k] = fmaf(rdlane(a, 25 + k), z1, acc[k]);
  }
  float ss = 0.f, qq = 0.f;
  #pragma unroll
  for (int k = 0; k < 25; ++k) {
    const int r = rb + k;
    const float d = dsb[r];
    const float h = fmaxf(d*(acc[k] + zb[(r << 6) + lane]) + bl, 0.f);
    h2g[((size_t)b*200 + r)*64 + lane] = h;
    ss += h; qq += h*h;
  }
  atomicAdd(&st[lane], ss);
  atomicAdd(&st[64 + lane], qq);
  __syncthreads();
  if (tid < 128) atomicAdd(&acc2g[tid], st[tid]);
}

// ---------- K6: inline BN-coeffs + layer-2 score + top-100 + Y3 = X3@W3 ----------
__global__ __launch_bounds__(512) void k_top2(
    const float* __restrict__ h2g, const float* __restrict__ acc2,
    const float* __restrict__ g2, const float* __restrict__ be2,
    const float* __restrict__ p2, const float* __restrict__ W3,
    const int* __restrict__ nodes2, int* __restrict__ nodes3,
    float* __restrict__ Y3) {
  __shared__ float sc[256]; __shared__ int si[256];
  __shared__ __align__(16) float xs[6400];
  __shared__ float sc2[64], sh2[64], cf2[64];
  __shared__ float c20s;
  const int tid = threadIdx.x;
  const int b = (blockIdx.x & 7)*32 + (blockIdx.x >> 3);   // XCD-swizzle
  if (tid < 64) {                       // inlined fin2
    const float S = acc2[tid], Q = acc2[64 + tid];
    const float N = 51200.f;
    const float mu = S/N, var = Q/N - mu*mu, inv = rsqrtf(var + EPSF);
    const float scale = inv*g2[tid], shift = be2[tid] - mu*scale;
    const float pv = p2[tid];
    const float pn = sqrtf(wave_sum(pv*pv));
    sc2[tid] = scale; sh2[tid] = shift; cf2[tid] = scale*pv/pn;
    const float u = wave_sum(shift*pv/pn);
    if (tid == 0) c20s = u;
  }
  __syncthreads();
  const int wave = tid >> 6, lane = tid & 63;
  const float cf = cf2[lane];
  const float c20 = c20s;
  for (int i = wave; i < 200; i += 8) {
    float v = h2g[((size_t)b*200 + i)*64 + lane] * cf;
    v = wave_sum(v);
    if (lane == 0) { sc[i] = v + c20; si[i] = i; }
  }
  if (tid >= 200 && tid < 256) { sc[tid] = -INFINITY; si[tid] = 0x7fffffff; }
  bitonic_desc(sc, si, 256);
  const float scale = sc2[lane], shift = sh2[lane];
  for (int o = tid; o < 6400; o += 512) {
    const int k = o >> 6;
    const int idx = si[k];
    const float tv = tanhf(sc[k]);
    xs[o] = (h2g[((size_t)b*200 + idx)*64 + lane] * scale + shift) * tv;
  }
  for (int k = tid; k < 100; k += 512) nodes3[b*100 + k] = nodes2[b*200 + si[k]];
  __syncthreads();
  // Y3 = X3 @ W3 (unscaled; dis3 folded into conv3)
  {
    const int g = tid & 127;
    float wr[64];
    #pragma unroll
    for (int f = 0; f < 64; ++f) wr[f] = W3[f*128 + g];
    for (int o = tid; o < 12800; o += 512) {
      const int k = o >> 7;
      float acc = 0.f;
      #pragma unroll
      for (int c4 = 0; c4 < 16; ++c4) {
        const float4 x4 = *(const float4*)&xs[(k<<6) + (c4<<2)];
        acc += x4.x*wr[c4*4] + x4.y*wr[c4*4+1] + x4.z*wr[c4*4+2] + x4.w*wr[c4*4+3];
      }
      Y3[(size_t)b*12800 + o] = acc;
    }
  }
}

// ---------- K7: gather A3 + dis3 (XCD-swizzled) ----------
__global__ __launch_bounds__(256) void k_gatherA3(
    const float* __restrict__ data, const int* __restrict__ nodes3,
    float* __restrict__ A3, float* __restrict__ dis3) {
  __shared__ int nds[100];
  const int slot = blockIdx.x >> 3;                 // 8 x 800
  const int b = (blockIdx.x & 7)*32 + slot/25, rg = slot % 25;
  const int tid = threadIdx.x;
  if (tid < 100) nds[tid] = nodes3[b*100 + tid];
  __syncthreads();
  const int wave = tid >> 6, lane = tid & 63;
  const int i = rg*4 + wave;
  const int ni = nds[i];
  const float* __restrict__ drow = data + (size_t)b*NE;
  float accd = 0.f;
  for (int j = lane; j < 100; j += 64) {
    float v = 0.f;
    if (j != i) {
      const int nj = nds[j];
      const int a = min(ni, nj), c = max(ni, nj);
      v = drow[tri_e(a, c)];
    }
    A3[((size_t)b*100 + i)*100 + j] = v;
    accd += v;
  }
  accd = wave_sum(accd);
  if (lane == 0) dis3[b*100 + i] = rsqrtf(1.f + accd);
}

// ---------- K8: conv3 via readlane broadcast, 4-j packed loads, 4-deep ring ----------
// grid = BB*2 (XCD-swizzled). Block p owns rows [p*50, p*50+50);
// wave w owns up to 13 rows. A-loads: lanes 0..51 carry 4 j's
// (q = lane/13, k = lane%13), ring of 4 -> 16 j's in flight.
__global__ __launch_bounds__(256) void k_conv3(
    const float* __restrict__ A3, const float* __restrict__ Y3,
    const float* __restrict__ dis3, const float* __restrict__ b3,
    float* __restrict__ h3g, float* __restrict__ acc3g) {
  __shared__ __align__(16) float zb[100*128];  // 51.2 KB, dis-scaled Y3
  __shared__ float dsb[100];
  __shared__ float st[256];
  const int tid = threadIdx.x;
  const int xcd = blockIdx.x & 7, slot = blockIdx.x >> 3;   // 8 x 64
  const int b = xcd*32 + (slot >> 1), p = slot & 1;
  const int wave = tid >> 6, lane = tid & 63;
  st[tid] = 0.f;
  if (tid < 100) dsb[tid] = dis3[b*100 + tid];
  for (int t = tid; t < 3200; t += 256) {
    const int row = t >> 5, f4 = t & 31;
    const float dz = dis3[b*100 + row];
    float4 v = *(const float4*)&Y3[((size_t)b*100 + row)*128 + (f4 << 2)];
    v.x *= dz; v.y *= dz; v.z *= dz; v.w *= dz;
    *(float4*)&zb[(row << 7) + (f4 << 2)] = v;
  }
  const float bl0 = b3[lane], bl1 = b3[64 + lane];
  __syncthreads();
  const int rb = p*50;
  const int lw = wave*13;
  const int lq = lane / 13;                     // sub-j within packed load (0..4)
  const int lk = lane - lq*13;                  // row index within wave
  const bool lv = (lane < 52) && (lw + lk < 50);
  auto ldA = [&](int j) -> float {
    return lv ? A3[((size_t)b*100 + j + lq)*100 + rb + lw + lk] : 0.f;
  };
  float acc0[13], acc1[13];
  #pragma unroll
  for (int k = 0; k < 13; ++k) { acc0[k] = 0.f; acc1[k] = 0.f; }
  float abuf[4];
  #pragma unroll
  for (int i = 0; i < 4; ++i) abuf[i] = ldA(4*i);
  #pragma unroll 1
  for (int jp = 0; jp < 25; ++jp) {
    const int j = jp << 2;
    float a;
    switch (jp & 3) {                 // static ring indexing
      case 0: a = abuf[0]; if (jp + 4 < 25) abuf[0] = ldA(j + 16); break;
      case 1: a = abuf[1]; if (jp + 4 < 25) abuf[1] = ldA(j + 16); break;
      case 2: a = abuf[2]; if (jp + 4 < 25) abuf[2] = ldA(j + 16); break;
      default: a = abuf[3]; if (jp + 4 < 25) abuf[3] = ldA(j + 16); break;
    }
    #pragma unroll
    for (int q = 0; q < 4; ++q) {
      const int jj = j + q;
      const float z0 = zb[(jj << 7) + lane];
      const float z1 = zb[(jj << 7) + 64 + lane];
      #pragma unroll
      for (int k = 0; k < 13; ++k) {
        const float av = rdlane(a, q*13 + k);
        acc0[k] = fmaf(av, z0, acc0[k]);
        acc1[k] = fmaf(av, z1, acc1[k]);
      }
    }
  }
  float ss0 = 0.f, qq0 = 0.f, ss1 = 0.f, qq1 = 0.f;
  #pragma unroll
  for (int k = 0; k < 13; ++k) {
    const int lr = lw + k;
    if (lr < 50) {
      const int r = rb + lr;
      const float d = dsb[r];
      const float h0 = fmaxf(d*(acc0[k] + zb[(r << 7) + lane]) + bl0, 0.f);
      const float h1 = fmaxf(d*(acc1[k] + zb[(r << 7) + 64 + lane]) + bl1, 0.f);
      h3g[((size_t)b*100 + r)*128 + lane] = h0;
      h3g[((size_t)b*100 + r)*128 + 64 + lane] = h1;
      ss0 += h0; qq0 += h0*h0; ss1 += h1; qq1 += h1*h1;
    }
  }
  atomicAdd(&st[lane], ss0);
  atomicAdd(&st[64 + lane], ss1);
  atomicAdd(&st[128 + lane], qq0);
  atomicAdd(&st[192 + lane], qq1);
  __syncthreads();
  atomicAdd(&acc3g[tid], st[tid]);
}

// ---------- K9: inline BN-coeffs + layer-3 score + top-50 + fused max-pool ----------
__global__ __launch_bounds__(256) void k_top3(
    const float* __restrict__ h3g, const float* __restrict__ acc3,
    const float* __restrict__ g3, const float* __restrict__ be3,
    const float* __restrict__ p3, float* __restrict__ out) {
  __shared__ float sc[128]; __shared__ int si[128]; __shared__ float tv[64];
  __shared__ float scl[128], shl[128], cfl[128];
  __shared__ float red2[4];
  const int tid = threadIdx.x;
  const int b = (blockIdx.x & 7)*32 + (blockIdx.x >> 3);   // XCD-swizzle
  const int wave = tid >> 6, lane = tid & 63;
  float scale = 0.f, shift = 0.f, pv = 0.f;
  if (tid < 128) {                      // inlined fin3
    const float S = acc3[tid], Q = acc3[128 + tid];
    const float N = 25600.f;
    const float mu = S/N, var = Q/N - mu*mu, inv = rsqrtf(var + EPSF);
    scale = inv*g3[tid]; shift = be3[tid] - mu*scale; pv = p3[tid];
    const float t2 = wave_sum(pv*pv);
    if (lane == 0) red2[wave] = t2;
  }
  __syncthreads();
  const float pn = sqrtf(red2[0] + red2[1]);
  if (tid < 128) {
    scl[tid] = scale; shl[tid] = shift; cfl[tid] = scale*pv/pn;
    const float u = wave_sum(shift*pv/pn);
    if (lane == 0) red2[2 + wave] = u;
  }
  __syncthreads();
  const float c30 = red2[2] + red2[3];
  const float clo = cfl[lane], chi = cfl[64 + lane];
  for (int i = wave; i < 100; i += 4) {
    const float* hr = h3g + ((size_t)b*100 + i)*128;
    float v = hr[lane]*clo + hr[64 + lane]*chi;
    v = wave_sum(v);
    if (lane == 0) { sc[i] = v + c30; si[i] = i; }
  }
  if (tid >= 100 && tid < 128) { sc[tid] = -INFINITY; si[tid] = 0x7fffffff; }
  bitonic_desc(sc, si, 128);
  if (tid < 50) tv[tid] = tanhf(sc[tid]);
  __syncthreads();
  if (tid < 128) {
    const float scalev = scl[tid], shiftv = shl[tid];
    float m = -INFINITY;
    for (int k = 0; k < 50; ++k) {
      const float h = h3g[((size_t)b*100 + si[k])*128 + tid];
      m = fmaxf(m, (h*scalev + shiftv)*tv[k]);
    }
    out[(size_t)b*128 + tid] = m;
  }
}

// ---------- host ----------
extern "C" void kernel_launch(void* const* d_in, const int* in_sizes, int n_in,
                              void* d_out, int out_size, void* d_ws, size_t ws_size,
                              hipStream_t stream) {
  (void)in_sizes; (void)n_in; (void)out_size; (void)ws_size;
  const float* data = (const float*)d_in[0];
  const float* W1 = (const float*)d_in[1];
  const float* b1 = (const float*)d_in[2];
  const float* g1 = (const float*)d_in[3];
  const float* be1 = (const float*)d_in[4];
  const float* p1 = (const float*)d_in[5];
  const float* W2 = (const float*)d_in[6];
  const float* b2 = (const float*)d_in[7];
  const float* g2 = (const float*)d_in[8];
  const float* be2 = (const float*)d_in[9];
  const float* p2 = (const float*)d_in[10];
  const float* W3 = (const float*)d_in[11];
  const float* b3 = (const float*)d_in[12];
  const float* g3 = (const float*)d_in[13];
  const float* be3 = (const float*)d_in[14];
  const float* p3 = (const float*)d_in[15];
  float* out = (float*)d_out;

  char* ws = (char*)d_ws;
  size_t off = 0;
  auto alloc = [&](size_t n) { size_t o = off; off += (n + 255) & ~(size_t)255; return o; };
  float* pr     = (float*)(ws + alloc((size_t)BB*49*64*4));
  float* pc     = (float*)(ws + alloc((size_t)BB*49*64*4));
  float* pr2    = (float*)(ws + alloc((size_t)BB*49*64*4));
  float* pc2    = (float*)(ws + alloc((size_t)BB*49*64*4));
  float* s1     = (float*)(ws + alloc((size_t)BB*NN0*4));
  float* accz   = (float*)(ws + alloc(448*4));   // acc1[64] | acc2[128] | acc3[256]
  int*   nodes2 = (int*)  (ws + alloc((size_t)BB*200*4));
  int*   sperm2 = (int*)  (ws + alloc((size_t)BB*200*4));
  float* Y2     = (float*)(ws + alloc((size_t)BB*12800*4));
  float* A2     = (float*)(ws + alloc((size_t)BB*40000*4));
  float* dis2   = (float*)(ws + alloc((size_t)BB*200*4));
  float* h2     = (float*)(ws + alloc((size_t)BB*12800*4));
  int*   nodes3 = (int*)  (ws + alloc((size_t)BB*100*4));
  float* Y3     = (float*)(ws + alloc((size_t)BB*12800*4));
  float* A3     = (float*)(ws + alloc((size_t)BB*10000*4));
  float* dis3   = (float*)(ws + alloc((size_t)BB*100*4));
  float* h3     = (float*)(ws + alloc((size_t)BB*12800*4));
  float* acc1 = accz;
  float* acc2 = accz + 64;
  float* acc3 = accz + 192;

  hipMemsetAsync(accz, 0, 448*4, stream);
  k_tri_mv<<<dim3(BB*7), dim3(256), 0, stream>>>(data, nullptr, nullptr, pr, pc);
  k_tri_mv<<<dim3(BB*7), dim3(256), 0, stream>>>(data, pr, pc, pr2, pc2);
  k_sfin_stats_red<<<dim3(400), dim3(256), 0, stream>>>(pr, pc, pr2, pc2, W1, b1, s1, acc1);
  k_top1<<<dim3(BB), dim3(512), 0, stream>>>(s1, acc1, W1, b1, g1, be1, p1, W2, nodes2, sperm2, Y2);
  k_gatherA2<<<dim3(BB*50), dim3(256), 0, stream>>>(data, nodes2, sperm2, A2, dis2);
  k_conv2<<<dim3(BB*2), dim3(256), 0, stream>>>(A2, Y2, dis2, b2, h2, acc2);
  k_top2<<<dim3(BB), dim3(512), 0, stream>>>(h2, acc2, g2, be2, p2, W3, nodes2, nodes3, Y3);
  k_gatherA3<<<dim3(BB*25), dim3(256), 0, stream>>>(data, nodes3, A3, dis3);
  k_conv3<<<dim3(BB*2), dim3(256), 0, stream>>>(A3, Y3, dis3, b3, h3, acc3);
  k_top3<<<dim3(BB), dim3(256), 0, stream>>>(h3, acc3, g3, be3, p3, out);
}

// Round 6
// 418.984 us; speedup vs baseline: 1.1523x; 1.0197x over previous
//
#include <hip/hip_runtime.h>
#include <math.h>

#define BB   256     // batch
#define NN0  400     // nodes at layer 1
#define NE   79800   // NN0*(NN0-1)/2
#define EPSF 1e-5f

// ---------- device helpers ----------
__device__ __forceinline__ int tri_e(int a, int c) {  // a<c, upper-tri flat index
  return a*(NN0-1) - ((a*(a-1))>>1) + (c - a - 1);
}

__device__ __forceinline__ size_t PRI(int b, int ti, int tj, int r) {
  return (((size_t)b*7 + ti)*7 + tj)*64 + r;
}

__device__ __forceinline__ float wave_sum(float v) {
  #pragma unroll
  for (int o = 32; o > 0; o >>= 1) v += __shfl_xor(v, o, 64);
  return v;
}

__device__ __forceinline__ float rdlane(float v, int k) {
  return __int_as_float(__builtin_amdgcn_readlane(__float_as_int(v), k));
}

// descending bitonic sort (score desc, idx asc == jax.lax.top_k order)
__device__ __forceinline__ void bitonic_desc(float* sc, int* si, int P) {
  const int tid = threadIdx.x;
  const int nt = blockDim.x;
  for (int k = 2; k <= P; k <<= 1) {
    for (int j = k >> 1; j > 0; j >>= 1) {
      __syncthreads();
      for (int i = tid; i < P; i += nt) {
        int ixj = i ^ j;
        if (ixj > i) {
          float a = sc[i], c = sc[ixj];
          int ai = si[i], ci = si[ixj];
          bool bef = (a > c) || (a == c && ai < ci);
          bool sw = ((i & k) == 0) ? !bef : bef;
          if (sw) { sc[i] = c; sc[ixj] = a; si[i] = ci; si[ixj] = ai; }
        }
      }
    }
  }
  __syncthreads();
}

// ---------- K1: dense symmetric tri-matvec partials (NO atomics) ----------
__global__ __launch_bounds__(256) void k_tri_mv(
    const float* __restrict__ data,
    const float* __restrict__ pr_in, const float* __restrict__ pc_in,
    float* __restrict__ pr, float* __restrict__ pc) {
  __shared__ float tile[64][65];
  __shared__ float dI[64], dJ[64];
  const int xcd = blockIdx.x & 7, slot = blockIdx.x >> 3;   // 8 x 224
  const int b = xcd*32 + slot/7, q0 = slot % 7;
  const int tid = threadIdx.x;
  const int wave = tid >> 6, lane = tid & 63;
  const float* __restrict__ drow = data + (size_t)b*NE;
  int ti_a[4], tj_a[4];
  #pragma unroll
  for (int u = 0; u < 4; ++u) {
    int t = q0 + u*7;
    int ti = 0, rem = t;
    while (rem >= 7 - ti) { rem -= 7 - ti; ++ti; }
    ti_a[u] = ti; tj_a[u] = ti + rem;
  }
  float vreg[16];
  float rI = 0.f, rJ = 0.f;
  auto issue = [&](int u) {
    const int i0 = ti_a[u]*64, j0 = tj_a[u]*64;
    const int ni = min(64, NN0 - i0), nj = min(64, NN0 - j0);
    #pragma unroll
    for (int k = 0; k < 16; ++k) {
      const int rr = wave*16 + k;
      const int i = i0 + rr, j = j0 + lane;
      vreg[k] = 0.f;
      if (rr < ni && lane < nj && j > i) vreg[k] = drow[tri_e(i, j)];
    }
    if (pr_in) {
      if (tid < 64) {
        float a = 0.f;
        if (tid < ni) {
          const int tt = ti_a[u], r = tid;
          float acc = 1.f;
          for (int tj = tt; tj < 7; ++tj) acc += pr_in[PRI(b, tt, tj, r)];
          for (int ts = 0; ts <= tt; ++ts) acc += pc_in[PRI(b, ts, tt, r)];
          a = rsqrtf(acc);
        }
        rI = a;
      } else if (tid < 128) {
        const int c = tid - 64;
        float a = 0.f;
        if (c < nj) {
          const int tt = tj_a[u], r = c;
          float acc = 1.f;
          for (int tj = tt; tj < 7; ++tj) acc += pr_in[PRI(b, tt, tj, r)];
          for (int ts = 0; ts <= tt; ++ts) acc += pc_in[PRI(b, ts, tt, r)];
          a = rsqrtf(acc);
        }
        rJ = a;
      }
    } else {
      if (tid < 64) rI = (tid < ni) ? 1.f : 0.f;
      else if (tid < 128) rJ = (tid - 64 < nj) ? 1.f : 0.f;
    }
  };
  issue(0);
  #pragma unroll 1
  for (int u = 0; u < 4; ++u) {
    const int ti = ti_a[u], tj = tj_a[u];
    if (u) __syncthreads();
    #pragma unroll
    for (int k = 0; k < 16; ++k) tile[wave*16 + k][lane] = vreg[k];
    if (tid < 64) dI[tid] = rI;
    else if (tid < 128) dJ[tid-64] = rJ;
    __syncthreads();
    if (u + 1 < 4) issue(u + 1);
    {
      const int r = tid >> 2, q = tid & 3;
      float s = 0.f;
      #pragma unroll
      for (int c = 0; c < 16; ++c) s += tile[r][q*16 + c] * dJ[q*16 + c];
      s += __shfl_xor(s, 1, 64);
      s += __shfl_xor(s, 2, 64);
      if (q == 0) pr[PRI(b, ti, tj, r)] = s;
    }
    {
      const int c = tid >> 2, q = tid & 3;
      float s = 0.f;
      #pragma unroll
      for (int r = 0; r < 16; ++r) s += tile[q*16 + r][c] * dI[q*16 + r];
      s += __shfl_xor(s, 1, 64);
      s += __shfl_xor(s, 2, 64);
      if (q == 0) pc[PRI(b, ti, tj, c)] = s;
    }
  }
}

// ---------- K2: reduce deg & s partials -> s1, + BN stats via global atomics ----------
__global__ __launch_bounds__(256) void k_sfin_stats_red(
    const float* __restrict__ pr, const float* __restrict__ pc,
    const float* __restrict__ pr2, const float* __restrict__ pc2,
    const float* __restrict__ W1, const float* __restrict__ b1,
    float* __restrict__ s1, float* __restrict__ acc1) {
  __shared__ float sl[256];
  __shared__ float st[64];
  __shared__ float w1s[32], b1s[32];
  const int tid = threadIdx.x;
  const int i = blockIdx.x*256 + tid;
  if (tid < 32) { w1s[tid] = W1[tid]; b1s[tid] = b1[tid]; }
  if (tid < 64) st[tid] = 0.f;
  const int b = i / NN0, n = i % NN0;
  const int t = n >> 6, r = n & 63;
  float dacc = 1.f, sacc = 0.f;
  for (int tj = t; tj < 7; ++tj) { dacc += pr[PRI(b, t, tj, r)]; sacc += pr2[PRI(b, t, tj, r)]; }
  for (int ti = 0; ti <= t; ++ti) { dacc += pc[PRI(b, ti, t, r)]; sacc += pc2[PRI(b, ti, t, r)]; }
  const float d = rsqrtf(dacc);
  const float s = d * (d + sacc);
  s1[i] = s;
  sl[tid] = s;
  __syncthreads();
  const int f = tid & 31, sub = tid >> 5;
  const float w = w1s[f], bb = b1s[f];
  float S = 0.f, Q = 0.f;
  #pragma unroll
  for (int k = 0; k < 32; ++k) {
    const float ss = sl[sub*32 + k];
    const float h = fmaxf(ss*w + bb, 0.f);
    S += h; Q += h*h;
  }
  atomicAdd(&st[f], S);
  atomicAdd(&st[32+f], Q);
  __syncthreads();
  if (tid < 64) atomicAdd(&acc1[tid], st[tid]);
}

// ---------- K3: inline BN-coeffs + layer-1 score + top-200 + Y2 = X2@W2 + perm ----------
__global__ __launch_bounds__(512) void k_top1(
    const float* __restrict__ s1, const float* __restrict__ acc1,
    const float* __restrict__ W1, const float* __restrict__ b1,
    const float* __restrict__ g1, const float* __restrict__ be1,
    const float* __restrict__ p1, const float* __restrict__ W2,
    int* __restrict__ nodes2, int* __restrict__ sperm2, float* __restrict__ Y2) {
  __shared__ float sc[512]; __shared__ int si[512];
  __shared__ float sS[NN0];
  __shared__ float tvs[200];
  __shared__ int nds_l[200];
  __shared__ float w1s[32], b1s[32], cfs[32], scs[32], shs[32];
  __shared__ __align__(16) float hp[6400];
  __shared__ float c0s;
  const int tid = threadIdx.x;
  const int b = (blockIdx.x & 7)*32 + (blockIdx.x >> 3);   // XCD-swizzle
  if (tid < 32) { w1s[tid] = W1[tid]; b1s[tid] = b1[tid]; }
  if (tid < 64) {                       // inlined fin1
    float scale = 0.f, shift = 0.f, pv = 0.f;
    if (tid < 32) {
      const float S = acc1[tid], Q = acc1[32 + tid];
      const float N = 102400.f;
      const float mu = S / N;
      const float var = Q / N - mu*mu;
      const float inv = rsqrtf(var + EPSF);
      scale = inv * g1[tid];
      shift = be1[tid] - mu * scale;
      pv = p1[tid];
    }
    const float pn = sqrtf(wave_sum(pv*pv));
    if (tid < 32) { scs[tid] = scale; shs[tid] = shift; cfs[tid] = scale*pv/pn; }
    float u = (tid < 32) ? shift*pv/pn : 0.f;
    u = wave_sum(u);
    if (tid == 0) c0s = u;
  }
  __syncthreads();
  const float c0 = c0s;
  {
    const int i = tid;
    if (i < NN0) {
      const float s = s1[(size_t)b*NN0 + i];
      sS[i] = s;
      float sco = c0;
      #pragma unroll
      for (int f = 0; f < 32; ++f) sco += fmaxf(s*w1s[f] + b1s[f], 0.f) * cfs[f];
      sc[i] = sco; si[i] = i;
    } else { sc[i] = -INFINITY; si[i] = 0x7fffffff; }
  }
  bitonic_desc(sc, si, 512);
  for (int k = tid; k < 200; k += 512) {
    tvs[k] = tanhf(sc[k]);
    nds_l[k] = si[k];
    nodes2[b*200 + k] = si[k];
  }
  __syncthreads();
  for (int o = tid; o < 6400; o += 512) {
    const int k = o >> 5, f = o & 31;
    const float s = sS[nds_l[k]];
    const float h = fmaxf(s*w1s[f] + b1s[f], 0.f);
    hp[o] = (h*scs[f] + shs[f]) * tvs[k];
  }
  __syncthreads();
  // Y2 = X2 @ W2 (unscaled; dis2 folded into A2')
  {
    const int g = tid & 63;
    float wr[32];
    #pragma unroll
    for (int f = 0; f < 32; ++f) wr[f] = W2[f*64 + g];
    for (int o = tid; o < 12800; o += 512) {
      const int k = o >> 6;
      float acc = 0.f;
      #pragma unroll
      for (int c4 = 0; c4 < 8; ++c4) {
        const float4 x4 = *(const float4*)&hp[(k<<5) + (c4<<2)];
        acc += x4.x*wr[c4*4] + x4.y*wr[c4*4+1] + x4.z*wr[c4*4+2] + x4.w*wr[c4*4+3];
      }
      Y2[(size_t)b*12800 + o] = acc;
    }
  }
  __syncthreads();
  if (tid < 256) {
    sc[tid] = (tid < 200) ? -(float)nds_l[tid] : -INFINITY;
    si[tid] = (tid < 200) ? tid : 0x7fffffff;
  }
  bitonic_desc(sc, si, 256);
  if (tid < 200) sperm2[b*200 + tid] = si[tid];
}

// ---------- K4: gather A2 (sorted-id order, XCD-swizzled), row-scaled by dis2 ----------
__global__ __launch_bounds__(256) void k_gatherA2(
    const float* __restrict__ data, const int* __restrict__ nodes2,
    const int* __restrict__ sperm2, float* __restrict__ A2, float* __restrict__ dis2) {
  __shared__ int nds[200], sp[200], sn[200];
  __shared__ float rowbuf[4][200];
  const int idx = blockIdx.x;
  const int r9 = idx >> 3;
  const int b = (idx & 7)*32 + r9/50;
  const int rg = r9 % 50;
  const int tid = threadIdx.x;
  if (tid < 200) { nds[tid] = nodes2[b*200 + tid]; sp[tid] = sperm2[b*200 + tid]; }
  __syncthreads();
  if (tid < 200) sn[tid] = nds[sp[tid]];
  __syncthreads();
  const int wave = tid >> 6, lane = tid & 63;
  const int i = rg*4 + wave;
  const int ni = nds[i];
  const float* __restrict__ drow = data + (size_t)b*NE;
  float accd = 0.f;
  for (int jj = lane; jj < 200; jj += 64) {
    const int sj = sn[jj];
    float v = 0.f;
    if (sj != ni) {
      const int a = min(ni, sj), c = max(ni, sj);
      v = drow[tri_e(a, c)];
    }
    rowbuf[wave][sp[jj]] = v;
    accd += v;
  }
  __syncthreads();
  accd = wave_sum(accd);
  const float dd = rsqrtf(1.f + accd);
  for (int j = lane; j < 200; j += 64)
    A2[((size_t)b*200 + i)*200 + j] = rowbuf[wave][j] * dd;   // dis-row-scaled
  if (lane == 0) dis2[b*200 + i] = dd;
}

// ---------- K5: conv2, readlane + z-from-global, double-buffered ----------
// grid = BB*4 (XCD-swizzled). Block p owns rows [p*50, p*50+50);
// wave w owns 13 rows (w*13+k < 50), lane = feature.
// A2' is dis_j-row-scaled, so acc = sum_j A[j][r]*d_j*Y2[j][lane] directly.
// A packed 4 j's per load (lq=lane/13, lk=lane%13, lanes 0..51);
// z = raw Y2[j][lane] coalesced global. Prefetch distance = 1 iter (+8/+12).
__global__ __launch_bounds__(256) void k_conv2(
    const float* __restrict__ A2, const float* __restrict__ Y2,
    const float* __restrict__ dis2, const float* __restrict__ b2,
    float* __restrict__ h2g, float* __restrict__ acc2g) {
  __shared__ float dsb[200];
  __shared__ float st[128];
  const int tid = threadIdx.x;
  const int xcd = blockIdx.x & 7, slot = blockIdx.x >> 3;   // 8 x 128
  const int b = xcd*32 + (slot >> 2), p = slot & 3;
  const int wave = tid >> 6, lane = tid & 63;
  if (tid < 128) st[tid] = 0.f;
  if (tid < 200) dsb[tid] = dis2[b*200 + tid];
  __syncthreads();
  const float bl = b2[lane];
  const int rbl = p*50 + wave*13;
  const int lq = lane / 13, lk = lane - lq*13;
  const bool lv = (lane < 52) && (wave*13 + lk < 50);
  const float* __restrict__ Ab = A2 + (size_t)b*40000;
  const float* __restrict__ Yb = Y2 + (size_t)b*12800;
  auto ldA = [&](int j4) -> float {         // quad base j4 -> rows j4..j4+3
    return lv ? Ab[(size_t)(j4 + lq)*200 + rbl + lk] : 0.f;
  };
  float acc[13];
  #pragma unroll
  for (int k = 0; k < 13; ++k) acc[k] = 0.f;
  float a0 = ldA(0), a1 = ldA(4);
  float z0[4], z1[4];
  #pragma unroll
  for (int q = 0; q < 4; ++q) z0[q] = Yb[q*64 + lane];
  #pragma unroll
  for (int q = 0; q < 4; ++q) z1[q] = Yb[(4 + q)*64 + lane];
  #pragma unroll 1
  for (int it = 0; it < 25; ++it) {
    const int j0 = it*8;
    { // body A: quad j0; prefetch quad j0+8 (next iter's body A)
      const float a = a0;
      float z[4];
      #pragma unroll
      for (int q = 0; q < 4; ++q) z[q] = z0[q];
      if (it < 24) {
        a0 = ldA(j0 + 8);
        #pragma unroll
        for (int q = 0; q < 4; ++q) z0[q] = Yb[(j0 + 8 + q)*64 + lane];
      }
      #pragma unroll
      for (int q = 0; q < 4; ++q) {
        #pragma unroll
        for (int k = 0; k < 13; ++k)
          acc[k] = fmaf(rdlane(a, q*13 + k), z[q], acc[k]);
      }
    }
    { // body B: quad j0+4; prefetch quad j0+12 (next iter's body B)
      const float a = a1;
      float z[4];
      #pragma unroll
      for (int q = 0; q < 4; ++q) z[q] = z1[q];
      if (it < 24) {
        a1 = ldA(j0 + 12);
        #pragma unroll
        for (int q = 0; q < 4; ++q) z1[q] = Yb[(j0 + 12 + q)*64 + lane];
      }
      #pragma unroll
      for (int q = 0; q < 4; ++q) {
        #pragma unroll
        for (int k = 0; k < 13; ++k)
          acc[k] = fmaf(rdlane(a, q*13 + k), z[q], acc[k]);
      }
    }
  }
  float ss = 0.f, qq = 0.f;
  #pragma unroll
  for (int k = 0; k < 13; ++k) {
    const int lr = wave*13 + k;
    if (lr < 50) {
      const int r = p*50 + lr;
      const float d = dsb[r];
      const float y = Yb[(size_t)r*64 + lane];
      const float h = fmaxf(d*acc[k] + d*(d*y) + bl, 0.f);
      h2g[((size_t)b*200 + r)*64 + lane] = h;
      ss += h; qq += h*h;
    }
  }
  atomicAdd(&st[lane], ss);
  atomicAdd(&st[64 + lane], qq);
  __syncthreads();
  if (tid < 128) atomicAdd(&acc2g[tid], st[tid]);
}

// ---------- K6: inline BN-coeffs + layer-2 score + top-100 + Y3 = X3@W3 ----------
__global__ __launch_bounds__(512) void k_top2(
    const float* __restrict__ h2g, const float* __restrict__ acc2,
    const float* __restrict__ g2, const float* __restrict__ be2,
    const float* __restrict__ p2, const float* __restrict__ W3,
    const int* __restrict__ nodes2, int* __restrict__ nodes3,
    float* __restrict__ Y3) {
  __shared__ float sc[256]; __shared__ int si[256];
  __shared__ __align__(16) float xs[6400];
  __shared__ float sc2[64], sh2[64], cf2[64];
  __shared__ float c20s;
  const int tid = threadIdx.x;
  const int b = (blockIdx.x & 7)*32 + (blockIdx.x >> 3);   // XCD-swizzle
  if (tid < 64) {                       // inlined fin2
    const float S = acc2[tid], Q = acc2[64 + tid];
    const float N = 51200.f;
    const float mu = S/N, var = Q/N - mu*mu, inv = rsqrtf(var + EPSF);
    const float scale = inv*g2[tid], shift = be2[tid] - mu*scale;
    const float pv = p2[tid];
    const float pn = sqrtf(wave_sum(pv*pv));
    sc2[tid] = scale; sh2[tid] = shift; cf2[tid] = scale*pv/pn;
    const float u = wave_sum(shift*pv/pn);
    if (tid == 0) c20s = u;
  }
  __syncthreads();
  const int wave = tid >> 6, lane = tid & 63;
  const float cf = cf2[lane];
  const float c20 = c20s;
  for (int i = wave; i < 200; i += 8) {
    float v = h2g[((size_t)b*200 + i)*64 + lane] * cf;
    v = wave_sum(v);
    if (lane == 0) { sc[i] = v + c20; si[i] = i; }
  }
  if (tid >= 200 && tid < 256) { sc[tid] = -INFINITY; si[tid] = 0x7fffffff; }
  bitonic_desc(sc, si, 256);
  const float scale = sc2[lane], shift = sh2[lane];
  for (int o = tid; o < 6400; o += 512) {
    const int k = o >> 6;
    const int idx = si[k];
    const float tv = tanhf(sc[k]);
    xs[o] = (h2g[((size_t)b*200 + idx)*64 + lane] * scale + shift) * tv;
  }
  for (int k = tid; k < 100; k += 512) nodes3[b*100 + k] = nodes2[b*200 + si[k]];
  __syncthreads();
  // Y3 = X3 @ W3 (unscaled; dis3 folded into A3')
  {
    const int g = tid & 127;
    float wr[64];
    #pragma unroll
    for (int f = 0; f < 64; ++f) wr[f] = W3[f*128 + g];
    for (int o = tid; o < 12800; o += 512) {
      const int k = o >> 7;
      float acc = 0.f;
      #pragma unroll
      for (int c4 = 0; c4 < 16; ++c4) {
        const float4 x4 = *(const float4*)&xs[(k<<6) + (c4<<2)];
        acc += x4.x*wr[c4*4] + x4.y*wr[c4*4+1] + x4.z*wr[c4*4+2] + x4.w*wr[c4*4+3];
      }
      Y3[(size_t)b*12800 + o] = acc;
    }
  }
}

// ---------- K7: gather A3 + dis3 (XCD-swizzled), row-scaled by dis3 ----------
__global__ __launch_bounds__(256) void k_gatherA3(
    const float* __restrict__ data, const int* __restrict__ nodes3,
    float* __restrict__ A3, float* __restrict__ dis3) {
  __shared__ int nds[100];
  const int slot = blockIdx.x >> 3;                 // 8 x 800
  const int b = (blockIdx.x & 7)*32 + slot/25, rg = slot % 25;
  const int tid = threadIdx.x;
  if (tid < 100) nds[tid] = nodes3[b*100 + tid];
  __syncthreads();
  const int wave = tid >> 6, lane = tid & 63;
  const int i = rg*4 + wave;
  const int ni = nds[i];
  const float* __restrict__ drow = data + (size_t)b*NE;
  const int j0 = lane, j1 = 64 + lane;
  float v0 = 0.f, v1 = 0.f;
  if (j0 != i) {
    const int nj = nds[j0];
    const int a = min(ni, nj), c = max(ni, nj);
    v0 = drow[tri_e(a, c)];
  }
  if (j1 < 100 && j1 != i) {
    const int nj = nds[j1];
    const int a = min(ni, nj), c = max(ni, nj);
    v1 = drow[tri_e(a, c)];
  }
  const float accd = wave_sum(v0 + v1);
  const float dd = rsqrtf(1.f + accd);
  A3[((size_t)b*100 + i)*100 + j0] = v0 * dd;       // dis-row-scaled
  if (j1 < 100) A3[((size_t)b*100 + i)*100 + j1] = v1 * dd;
  if (lane == 0) dis3[b*100 + i] = dd;
}

// ---------- K8: conv3, readlane + z-from-global, double-buffered ----------
// grid = BB*4 (XCD-swizzled). Block p owns rows [p*25, p*25+25);
// wave w owns 7 rows (w*7+k < 25), lane = feats {lane, 64+lane}.
// A packed 4 j's per load (lq=lane/7<4, lk=lane%7, lanes 0..27).
// Prefetch distance = 1 iter (+8/+12); tail quad 96 lands in buf0 at it=11.
__global__ __launch_bounds__(256) void k_conv3(
    const float* __restrict__ A3, const float* __restrict__ Y3,
    const float* __restrict__ dis3, const float* __restrict__ b3,
    float* __restrict__ h3g, float* __restrict__ acc3g) {
  __shared__ float dsb[100];
  __shared__ float st[256];
  const int tid = threadIdx.x;
  const int xcd = blockIdx.x & 7, slot = blockIdx.x >> 3;   // 8 x 128
  const int b = xcd*32 + (slot >> 2), p = slot & 3;
  const int wave = tid >> 6, lane = tid & 63;
  st[tid] = 0.f;
  if (tid < 100) dsb[tid] = dis3[b*100 + tid];
  __syncthreads();
  const float bl0 = b3[lane], bl1 = b3[64 + lane];
  const int rbl = p*25 + wave*7;
  const int lq = lane / 7, lk = lane - lq*7;
  const bool lv = (lq < 4) && (wave*7 + lk < 25);
  const float* __restrict__ Ab = A3 + (size_t)b*10000;
  const float* __restrict__ Yb = Y3 + (size_t)b*12800;
  auto ldA = [&](int j4) -> float {
    return lv ? Ab[(size_t)(j4 + lq)*100 + rbl + lk] : 0.f;
  };
  float ac0[7], ac1[7];
  #pragma unroll
  for (int k = 0; k < 7; ++k) { ac0[k] = 0.f; ac1[k] = 0.f; }
  float a0 = ldA(0), a1 = ldA(4);
  float z0[8], z1[8];              // [2q] = feat lane, [2q+1] = feat 64+lane
  #pragma unroll
  for (int q = 0; q < 4; ++q) {
    z0[2*q] = Yb[q*128 + lane];       z0[2*q+1] = Yb[q*128 + 64 + lane];
    z1[2*q] = Yb[(4+q)*128 + lane];   z1[2*q+1] = Yb[(4+q)*128 + 64 + lane];
  }
  #pragma unroll 1
  for (int it = 0; it < 12; ++it) {
    const int j0 = it*8;
    { // body A: quad j0; prefetch quad j0+8 (valid through it=11 -> quad 96)
      const float a = a0;
      float z[8];
      #pragma unroll
      for (int q = 0; q < 8; ++q) z[q] = z0[q];
      a0 = ldA(j0 + 8);
      #pragma unroll
      for (int q = 0; q < 4; ++q) {
        z0[2*q]   = Yb[(j0 + 8 + q)*128 + lane];
        z0[2*q+1] = Yb[(j0 + 8 + q)*128 + 64 + lane];
      }
      #pragma unroll
      for (int q = 0; q < 4; ++q) {
        #pragma unroll
        for (int k = 0; k < 7; ++k) {
          const float av = rdlane(a, q*7 + k);
          ac0[k] = fmaf(av, z[2*q], ac0[k]);
          ac1[k] = fmaf(av, z[2*q+1], ac1[k]);
        }
      }
    }
    { // body B: quad j0+4; prefetch quad j0+12 (guarded: last valid at it=10)
      const float a = a1;
      float z[8];
      #pragma unroll
      for (int q = 0; q < 8; ++q) z[q] = z1[q];
      if (it < 11) {
        a1 = ldA(j0 + 12);
        #pragma unroll
        for (int q = 0; q < 4; ++q) {
          z1[2*q]   = Yb[(j0 + 12 + q)*128 + lane];
          z1[2*q+1] = Yb[(j0 + 12 + q)*128 + 64 + lane];
        }
      }
      #pragma unroll
      for (int q = 0; q < 4; ++q) {
        #pragma unroll
        for (int k = 0; k < 7; ++k) {
          const float av = rdlane(a, q*7 + k);
          ac0[k] = fmaf(av, z[2*q], ac0[k]);
          ac1[k] = fmaf(av, z[2*q+1], ac1[k]);
        }
      }
    }
  }
  { // tail: quad 96 (j = 96..99), loaded into buf0 at it=11 body A
    const float a = a0;
    #pragma unroll
    for (int q = 0; q < 4; ++q) {
      #pragma unroll
      for (int k = 0; k < 7; ++k) {
        const float av = rdlane(a, q*7 + k);
        ac0[k] = fmaf(av, z0[2*q], ac0[k]);
        ac1[k] = fmaf(av, z0[2*q+1], ac1[k]);
      }
    }
  }
  float ss0 = 0.f, qq0 = 0.f, ss1 = 0.f, qq1 = 0.f;
  #pragma unroll
  for (int k = 0; k < 7; ++k) {
    const int lr = wave*7 + k;
    if (lr < 25) {
      const int r = p*25 + lr;
      const float d = dsb[r];
      const float y0 = Yb[(size_t)r*128 + lane];
      const float y1 = Yb[(size_t)r*128 + 64 + lane];
      const float h0 = fmaxf(d*ac0[k] + d*(d*y0) + bl0, 0.f);
      const float h1 = fmaxf(d*ac1[k] + d*(d*y1) + bl1, 0.f);
      h3g[((size_t)b*100 + r)*128 + lane] = h0;
      h3g[((size_t)b*100 + r)*128 + 64 + lane] = h1;
      ss0 += h0; qq0 += h0*h0; ss1 += h1; qq1 += h1*h1;
    }
  }
  atomicAdd(&st[lane], ss0);
  atomicAdd(&st[64 + lane], ss1);
  atomicAdd(&st[128 + lane], qq0);
  atomicAdd(&st[192 + lane], qq1);
  __syncthreads();
  atomicAdd(&acc3g[tid], st[tid]);
}

// ---------- K9: inline BN-coeffs + layer-3 score + top-50 + fused max-pool ----------
__global__ __launch_bounds__(256) void k_top3(
    const float* __restrict__ h3g, const float* __restrict__ acc3,
    const float* __restrict__ g3, const float* __restrict__ be3,
    const float* __restrict__ p3, float* __restrict__ out) {
  __shared__ float sc[128]; __shared__ int si[128]; __shared__ float tv[64];
  __shared__ float scl[128], shl[128], cfl[128];
  __shared__ float red2[4];
  const int tid = threadIdx.x;
  const int b = (blockIdx.x & 7)*32 + (blockIdx.x >> 3);   // XCD-swizzle
  const int wave = tid >> 6, lane = tid & 63;
  float scale = 0.f, shift = 0.f, pv = 0.f;
  if (tid < 128) {                      // inlined fin3
    const float S = acc3[tid], Q = acc3[128 + tid];
    const float N = 25600.f;
    const float mu = S/N, var = Q/N - mu*mu, inv = rsqrtf(var + EPSF);
    scale = inv*g3[tid]; shift = be3[tid] - mu*scale; pv = p3[tid];
    const float t2 = wave_sum(pv*pv);
    if (lane == 0) red2[wave] = t2;
  }
  __syncthreads();
  const float pn = sqrtf(red2[0] + red2[1]);
  if (tid < 128) {
    scl[tid] = scale; shl[tid] = shift; cfl[tid] = scale*pv/pn;
    const float u = wave_sum(shift*pv/pn);
    if (lane == 0) red2[2 + wave] = u;
  }
  __syncthreads();
  const float c30 = red2[2] + red2[3];
  const float clo = cfl[lane], chi = cfl[64 + lane];
  for (int i = wave; i < 100; i += 4) {
    const float* hr = h3g + ((size_t)b*100 + i)*128;
    float v = hr[lane]*clo + hr[64 + lane]*chi;
    v = wave_sum(v);
    if (lane == 0) { sc[i] = v + c30; si[i] = i; }
  }
  if (tid >= 100 && tid < 128) { sc[tid] = -INFINITY; si[tid] = 0x7fffffff; }
  bitonic_desc(sc, si, 128);
  if (tid < 50) tv[tid] = tanhf(sc[tid]);
  __syncthreads();
  if (tid < 128) {
    const float scalev = scl[tid], shiftv = shl[tid];
    float m = -INFINITY;
    for (int k = 0; k < 50; ++k) {
      const float h = h3g[((size_t)b*100 + si[k])*128 + tid];
      m = fmaxf(m, (h*scalev + shiftv)*tv[k]);
    }
    out[(size_t)b*128 + tid] = m;
  }
}

// ---------- host ----------
extern "C" void kernel_launch(void* const* d_in, const int* in_sizes, int n_in,
                              void* d_out, int out_size, void* d_ws, size_t ws_size,
                              hipStream_t stream) {
  (void)in_sizes; (void)n_in; (void)out_size; (void)ws_size;
  const float* data = (const float*)d_in[0];
  const float* W1 = (const float*)d_in[1];
  const float* b1 = (const float*)d_in[2];
  const float* g1 = (const float*)d_in[3];
  const float* be1 = (const float*)d_in[4];
  const float* p1 = (const float*)d_in[5];
  const float* W2 = (const float*)d_in[6];
  const float* b2 = (const float*)d_in[7];
  const float* g2 = (const float*)d_in[8];
  const float* be2 = (const float*)d_in[9];
  const float* p2 = (const float*)d_in[10];
  const float* W3 = (const float*)d_in[11];
  const float* b3 = (const float*)d_in[12];
  const float* g3 = (const float*)d_in[13];
  const float* be3 = (const float*)d_in[14];
  const float* p3 = (const float*)d_in[15];
  float* out = (float*)d_out;

  char* ws = (char*)d_ws;
  size_t off = 0;
  auto alloc = [&](size_t n) { size_t o = off; off += (n + 255) & ~(size_t)255; return o; };
  float* pr     = (float*)(ws + alloc((size_t)BB*49*64*4));
  float* pc     = (float*)(ws + alloc((size_t)BB*49*64*4));
  float* pr2    = (float*)(ws + alloc((size_t)BB*49*64*4));
  float* pc2    = (float*)(ws + alloc((size_t)BB*49*64*4));
  float* s1     = (float*)(ws + alloc((size_t)BB*NN0*4));
  float* accz   = (float*)(ws + alloc(448*4));   // acc1[64] | acc2[128] | acc3[256]
  int*   nodes2 = (int*)  (ws + alloc((size_t)BB*200*4));
  int*   sperm2 = (int*)  (ws + alloc((size_t)BB*200*4));
  float* Y2     = (float*)(ws + alloc((size_t)BB*12800*4));
  float* A2     = (float*)(ws + alloc((size_t)BB*40000*4));
  float* dis2   = (float*)(ws + alloc((size_t)BB*200*4));
  float* h2     = (float*)(ws + alloc((size_t)BB*12800*4));
  int*   nodes3 = (int*)  (ws + alloc((size_t)BB*100*4));
  float* Y3     = (float*)(ws + alloc((size_t)BB*12800*4));
  float* A3     = (float*)(ws + alloc((size_t)BB*10000*4));
  float* dis3   = (float*)(ws + alloc((size_t)BB*100*4));
  float* h3     = (float*)(ws + alloc((size_t)BB*12800*4));
  float* acc1 = accz;
  float* acc2 = accz + 64;
  float* acc3 = accz + 192;

  hipMemsetAsync(accz, 0, 448*4, stream);
  k_tri_mv<<<dim3(BB*7), dim3(256), 0, stream>>>(data, nullptr, nullptr, pr, pc);
  k_tri_mv<<<dim3(BB*7), dim3(256), 0, stream>>>(data, pr, pc, pr2, pc2);
  k_sfin_stats_red<<<dim3(400), dim3(256), 0, stream>>>(pr, pc, pr2, pc2, W1, b1, s1, acc1);
  k_top1<<<dim3(BB), dim3(512), 0, stream>>>(s1, acc1, W1, b1, g1, be1, p1, W2, nodes2, sperm2, Y2);
  k_gatherA2<<<dim3(BB*50), dim3(256), 0, stream>>>(data, nodes2, sperm2, A2, dis2);
  k_conv2<<<dim3(BB*4), dim3(256), 0, stream>>>(A2, Y2, dis2, b2, h2, acc2);
  k_top2<<<dim3(BB), dim3(512), 0, stream>>>(h2, acc2, g2, be2, p2, W3, nodes2, nodes3, Y3);
  k_gatherA3<<<dim3(BB*25), dim3(256), 0, stream>>>(data, nodes3, A3, dis3);
  k_conv3<<<dim3(BB*4), dim3(256), 0, stream>>>(A3, Y3, dis3, b3, h3, acc3);
  k_top3<<<dim3(BB), dim3(256), 0, stream>>>(h3, acc3, g3, be3, p3, out);
}